// Round 5
// baseline (548.010 us; speedup 1.0000x reference)
//
#include <hip/hip_runtime.h>
#include <math.h>

// Problem constants (from reference)
#define N_G   60000
#define N_D   40000
#define NTOT  100000          // N_G + N_D
#define DIM   64
#define E_EDGES 1600000
#define B_BATCH 4096
#define K_NEG   1
#define DECAY_F 1e-4f
#define NB_SCAN ((NTOT + 1023) / 1024)   // 98 blocks for the hierarchical scan

// ---------------------------------------------------------------------------
// CSR build: histogram -> hierarchical scan (3 kernels) -> scatter (packed int2)
// ---------------------------------------------------------------------------
__global__ void k_count(const int* __restrict__ arow, int* __restrict__ cnt) {
    int e = blockIdx.x * blockDim.x + threadIdx.x;
    if (e >= E_EDGES) return;
    atomicAdd(&cnt[arow[e]], 1);
}

// scan1: per-block (1024 elems) exclusive scan of cnt -> row_ptr; block totals.
__global__ void k_scan1(const int* __restrict__ cnt, int* __restrict__ row_ptr,
                        int* __restrict__ blocksum) {
    int gid  = blockIdx.x * 1024 + threadIdx.x;
    int lane = threadIdx.x & 63;
    int wid  = threadIdx.x >> 6;           // 16 waves
    int v = (gid < NTOT) ? cnt[gid] : 0;
    int x = v;
    #pragma unroll
    for (int off = 1; off < 64; off <<= 1) {
        int y = __shfl_up(x, off);
        if (lane >= off) x += y;
    }
    __shared__ int wsum[16];
    if (lane == 63) wsum[wid] = x;
    __syncthreads();
    if (wid == 0) {
        int w = (lane < 16) ? wsum[lane] : 0;
        #pragma unroll
        for (int off = 1; off < 16; off <<= 1) {
            int y = __shfl_up(w, off);
            if (lane >= off) w += y;
        }
        if (lane < 16) wsum[lane] = w;     // inclusive wave-sum scan
    }
    __syncthreads();
    int woff = (wid == 0) ? 0 : wsum[wid - 1];
    int incl = x + woff;
    if (gid < NTOT) row_ptr[gid] = incl - v;   // block-local exclusive
    if (threadIdx.x == 1023) blocksum[blockIdx.x] = incl;
}

// scan2: exclusive scan of the 98 block sums (single small block, 2 waves).
__global__ void k_scan2(const int* __restrict__ blocksum, int* __restrict__ blockoff) {
    int t = threadIdx.x;                   // 0..127
    int lane = t & 63;
    int wid  = t >> 6;
    int v = (t < NB_SCAN) ? blocksum[t] : 0;
    int x = v;
    #pragma unroll
    for (int off = 1; off < 64; off <<= 1) {
        int y = __shfl_up(x, off);
        if (lane >= off) x += y;
    }
    __shared__ int wsum[2];
    if (lane == 63) wsum[wid] = x;
    __syncthreads();
    int incl = x + ((wid == 1) ? wsum[0] : 0);
    if (t < NB_SCAN) blockoff[t] = incl - v;
}

// scan3: add block offsets in place; mirror into cursor; set sentinel.
__global__ void k_scan3(int* __restrict__ row_ptr, const int* __restrict__ blockoff,
                        int* __restrict__ cursor) {
    int gid = blockIdx.x * blockDim.x + threadIdx.x;
    if (gid < NTOT) {
        int r = row_ptr[gid] + blockoff[gid >> 10];
        row_ptr[gid] = r;
        cursor[gid]  = r;
    }
    if (gid == 0) row_ptr[NTOT] = E_EDGES;
}

__global__ void k_scatter(const int* __restrict__ arow, const int* __restrict__ acol,
                          const float* __restrict__ aval, int* __restrict__ cursor,
                          int2* __restrict__ edge_s) {
    int e = blockIdx.x * blockDim.x + threadIdx.x;
    if (e >= E_EDGES) return;
    int r = arow[e];
    int pos = atomicAdd(&cursor[r], 1);
    edge_s[pos] = make_int2(acol[e], __float_as_int(aval[e]));
}

// ---------------------------------------------------------------------------
// Hop 1: side1[row] = sum val * raw[col]   (raw = concat(ge, de), read in place)
// One wave64 per row; lane l holds element l. Unroll x8; masked-batch tail so
// the remainder's gathers also issue in parallel (no serial dependent chain).
// ---------------------------------------------------------------------------
__global__ void spmm_first(const int* __restrict__ row_ptr, const int2* __restrict__ edge_s,
                           const float* __restrict__ ge, const float* __restrict__ de,
                           float* __restrict__ side1) {
    int gtid = blockIdx.x * blockDim.x + threadIdx.x;
    int row  = gtid >> 6;
    int lane = gtid & 63;
    if (row >= NTOT) return;
    int s = row_ptr[row];
    int e = row_ptr[row + 1];
    float acc0 = 0.0f, acc1 = 0.0f;
    for (; s + 8 <= e; s += 8) {
        int2 ed[8];
        #pragma unroll
        for (int i = 0; i < 8; ++i) ed[i] = edge_s[s + i];
        float a[8];
        #pragma unroll
        for (int i = 0; i < 8; ++i) {
            int c = ed[i].x;
            const float* base = (c < N_G) ? (ge + (size_t)c * DIM)
                                          : (de + (size_t)(c - N_G) * DIM);
            a[i] = base[lane];
        }
        #pragma unroll
        for (int i = 0; i < 8; i += 2) {
            acc0 = fmaf(__int_as_float(ed[i].y),     a[i],     acc0);
            acc1 = fmaf(__int_as_float(ed[i + 1].y), a[i + 1], acc1);
        }
    }
    if (s < e) {                                  // masked tail batch
        int2 ed[8];
        #pragma unroll
        for (int i = 0; i < 8; ++i)
            ed[i] = (s + i < e) ? edge_s[s + i] : make_int2(0, 0);
        float a[8];
        #pragma unroll
        for (int i = 0; i < 8; ++i) {
            int c = ed[i].x;
            const float* base = (c < N_G) ? (ge + (size_t)c * DIM)
                                          : (de + (size_t)(c - N_G) * DIM);
            a[i] = base[lane];
        }
        #pragma unroll
        for (int i = 0; i < 8; i += 2) {
            acc0 = fmaf(__int_as_float(ed[i].y),     a[i],     acc0);
            acc1 = fmaf(__int_as_float(ed[i + 1].y), a[i + 1], acc1);
        }
    }
    side1[(size_t)row * DIM + lane] = acc0 + acc1;
}

// ---------------------------------------------------------------------------
// Hop 2: side2[row] = sum val * side1[col]
// ---------------------------------------------------------------------------
__global__ void spmm_mid(const int* __restrict__ row_ptr, const int2* __restrict__ edge_s,
                         const float* __restrict__ src, float* __restrict__ dst) {
    int gtid = blockIdx.x * blockDim.x + threadIdx.x;
    int row  = gtid >> 6;
    int lane = gtid & 63;
    if (row >= NTOT) return;
    int s = row_ptr[row];
    int e = row_ptr[row + 1];
    float acc0 = 0.0f, acc1 = 0.0f;
    for (; s + 8 <= e; s += 8) {
        int2 ed[8];
        #pragma unroll
        for (int i = 0; i < 8; ++i) ed[i] = edge_s[s + i];
        float a[8];
        #pragma unroll
        for (int i = 0; i < 8; ++i) a[i] = src[(size_t)ed[i].x * DIM + lane];
        #pragma unroll
        for (int i = 0; i < 8; i += 2) {
            acc0 = fmaf(__int_as_float(ed[i].y),     a[i],     acc0);
            acc1 = fmaf(__int_as_float(ed[i + 1].y), a[i + 1], acc1);
        }
    }
    if (s < e) {                                  // masked tail batch
        int2 ed[8];
        #pragma unroll
        for (int i = 0; i < 8; ++i)
            ed[i] = (s + i < e) ? edge_s[s + i] : make_int2(0, 0);
        float a[8];
        #pragma unroll
        for (int i = 0; i < 8; ++i) a[i] = src[(size_t)ed[i].x * DIM + lane];
        #pragma unroll
        for (int i = 0; i < 8; i += 2) {
            acc0 = fmaf(__int_as_float(ed[i].y),     a[i],     acc0);
            acc1 = fmaf(__int_as_float(ed[i + 1].y), a[i + 1], acc1);
        }
    }
    dst[(size_t)row * DIM + lane] = acc0 + acc1;
}

// ---------------------------------------------------------------------------
// Hop-3 pull for a single row: sum val * src[col], unroll 8 + masked tail.
// ---------------------------------------------------------------------------
__device__ __forceinline__ float pull_row(const int* __restrict__ row_ptr,
                                          const int2* __restrict__ edge_s,
                                          const float* __restrict__ src,
                                          int row, int lane) {
    int s = row_ptr[row];
    int e = row_ptr[row + 1];
    float acc0 = 0.0f, acc1 = 0.0f;
    for (; s + 8 <= e; s += 8) {
        int2 ed[8];
        #pragma unroll
        for (int i = 0; i < 8; ++i) ed[i] = edge_s[s + i];
        float a[8];
        #pragma unroll
        for (int i = 0; i < 8; ++i) a[i] = src[(size_t)ed[i].x * DIM + lane];
        #pragma unroll
        for (int i = 0; i < 8; i += 2) {
            acc0 = fmaf(__int_as_float(ed[i].y),     a[i],     acc0);
            acc1 = fmaf(__int_as_float(ed[i + 1].y), a[i + 1], acc1);
        }
    }
    if (s < e) {
        int2 ed[8];
        #pragma unroll
        for (int i = 0; i < 8; ++i)
            ed[i] = (s + i < e) ? edge_s[s + i] : make_int2(0, 0);
        float a[8];
        #pragma unroll
        for (int i = 0; i < 8; ++i) a[i] = src[(size_t)ed[i].x * DIM + lane];
        #pragma unroll
        for (int i = 0; i < 8; i += 2) {
            acc0 = fmaf(__int_as_float(ed[i].y),     a[i],     acc0);
            acc1 = fmaf(__int_as_float(ed[i + 1].y), a[i + 1], acc1);
        }
    }
    return acc0 + acc1;
}

// ---------------------------------------------------------------------------
// mean_rows: one wave per (batch, row-type). 3*B waves.
// Computes mean = 0.25 * (w0*raw + w1*side1 + w2*side2 + w3*pull(side2)) for
// its row into mrows, and atomically adds its hop-0 reg contribution.
// ---------------------------------------------------------------------------
__global__ void mean_rows(const float* __restrict__ side1, const float* __restrict__ side2,
                          const int* __restrict__ row_ptr, const int2* __restrict__ edge_s,
                          const float* __restrict__ ge, const float* __restrict__ de,
                          const float* __restrict__ gt, const float* __restrict__ dt,
                          const int* __restrict__ user, const int* __restrict__ pos,
                          const int* __restrict__ neg, float* __restrict__ mrows,
                          float* __restrict__ accum) {
    int gtid = blockIdx.x * blockDim.x + threadIdx.x;
    int wave = gtid >> 6;                  // 0 .. 3*B-1
    int lane = gtid & 63;
    if (wave >= 3 * B_BATCH) return;
    int b = wave / 3;
    int j = wave - 3 * b;                  // 0=user, 1=pos, 2=neg

    int   row;
    float t, e0;
    if (j == 0) {
        int u = user[b];
        row = u;  t = gt[u];  e0 = ge[(size_t)u * DIM + lane];
    } else {
        int d = (j == 1) ? pos[b] : neg[b * K_NEG];
        row = N_G + d;  t = dt[d];  e0 = de[(size_t)d * DIM + lane];
    }
    float w0 = expf(-t);
    float w1 = w0 * t;
    float w2 = w1 * t * 0.5f;
    float w3 = w1 * t * t * (1.0f / 6.0f);

    float s1 = side1[(size_t)row * DIM + lane];
    float s2 = side2[(size_t)row * DIM + lane];
    float s3 = pull_row(row_ptr, edge_s, side2, row, lane);
    float m  = 0.25f * (w0 * e0 + w1 * s1 + w2 * s2 + w3 * s3);
    mrows[(size_t)wave * DIM + lane] = m;

    // hop-0 regularization contribution for this row occurrence
    float r0 = w0 * e0;
    float reg = r0 * r0;
    #pragma unroll
    for (int off = 32; off > 0; off >>= 1) reg += __shfl_down(reg, off);
    if (lane == 0) atomicAdd(&accum[1], reg);
}

// ---------------------------------------------------------------------------
// loss_dot: one wave per batch element; reads the 3 mean rows (L2-hot).
// ---------------------------------------------------------------------------
__global__ void loss_dot(const float* __restrict__ mrows, float* __restrict__ accum) {
    int gtid = blockIdx.x * blockDim.x + threadIdx.x;
    int b    = gtid >> 6;
    int lane = gtid & 63;
    if (b >= B_BATCH) return;
    float gm = mrows[(size_t)(3 * b + 0) * DIM + lane];
    float pm = mrows[(size_t)(3 * b + 1) * DIM + lane];
    float nm = mrows[(size_t)(3 * b + 2) * DIM + lane];
    float dotp = gm * pm;
    float dotn = gm * nm;
    #pragma unroll
    for (int off = 32; off > 0; off >>= 1) {
        dotp += __shfl_down(dotp, off);
        dotn += __shfl_down(dotn, off);
    }
    if (lane == 0) {
        float x = dotn - dotp;
        float mf = fmaxf(x, 0.0f) + log1pf(expf(-fabsf(x)));   // log1p(exp(x))
        atomicAdd(&accum[0], mf);
    }
}

__global__ void finalize(const float* __restrict__ accum, float* __restrict__ out) {
    float mf  = accum[0] / (float)B_BATCH;
    float emb = DECAY_F * (accum[1] * 0.5f) / (float)B_BATCH;
    out[0] = mf + emb;
    out[1] = mf;
    out[2] = emb;
}

extern "C" void kernel_launch(void* const* d_in, const int* in_sizes, int n_in,
                              void* d_out, int out_size, void* d_ws, size_t ws_size,
                              hipStream_t stream) {
    const float* ge   = (const float*)d_in[0];
    const float* de   = (const float*)d_in[1];
    const float* gt   = (const float*)d_in[2];
    const float* dt   = (const float*)d_in[3];
    const float* aval = (const float*)d_in[4];
    const int*   arow = (const int*)d_in[5];
    const int*   acol = (const int*)d_in[6];
    const int*   user = (const int*)d_in[7];
    const int*   pos  = (const int*)d_in[8];
    const int*   neg  = (const int*)d_in[9];
    float* out = (float*)d_out;

    // Workspace layout (~68.5 MB)
    char* ws = (char*)d_ws;
    const size_t bufBytes = (size_t)NTOT * DIM * sizeof(float);
    float* side1    = (float*)(ws);
    float* side2    = (float*)(ws + bufBytes);
    char*  p        = ws + 2 * bufBytes;
    int*   row_ptr  = (int*)p;             p += (NTOT + 1) * sizeof(int);
    int*   cnt      = (int*)p;             p += NTOT * sizeof(int);
    int*   cursor   = (int*)p;             p += NTOT * sizeof(int);
    int*   blocksum = (int*)p;             p += NB_SCAN * sizeof(int);
    int*   blockoff = (int*)p;             p += NB_SCAN * sizeof(int);
    int2*  edge_s   = (int2*)p;            p += (size_t)E_EDGES * sizeof(int2);
    float* mrows    = (float*)p;           p += (size_t)3 * B_BATCH * DIM * sizeof(float);
    float* accum    = (float*)p;

    hipMemsetAsync(cnt, 0, NTOT * sizeof(int), stream);
    hipMemsetAsync(accum, 0, 2 * sizeof(float), stream);

    // CSR build (reused by all hops)
    k_count <<<(E_EDGES + 255) / 256, 256, 0, stream>>>(arow, cnt);
    k_scan1 <<<NB_SCAN, 1024, 0, stream>>>(cnt, row_ptr, blocksum);
    k_scan2 <<<1, 128, 0, stream>>>(blocksum, blockoff);
    k_scan3 <<<(NTOT + 255) / 256, 256, 0, stream>>>(row_ptr, blockoff, cursor);
    k_scatter<<<(E_EDGES + 255) / 256, 256, 0, stream>>>(arow, acol, aval, cursor, edge_s);

    const int spmm_blocks = (NTOT * 64 + 255) / 256;
    spmm_first<<<spmm_blocks, 256, 0, stream>>>(row_ptr, edge_s, ge, de, side1);
    spmm_mid  <<<spmm_blocks, 256, 0, stream>>>(row_ptr, edge_s, side1, side2);

    mean_rows<<<(3 * B_BATCH * 64 + 255) / 256, 256, 0, stream>>>(
        side1, side2, row_ptr, edge_s, ge, de, gt, dt, user, pos, neg, mrows, accum);
    loss_dot<<<(B_BATCH * 64 + 255) / 256, 256, 0, stream>>>(mrows, accum);
    finalize<<<1, 1, 0, stream>>>(accum, out);
}

// Round 6
// 352.050 us; speedup vs baseline: 1.5566x; 1.5566x over previous
//
#include <hip/hip_runtime.h>
#include <math.h>

// Problem constants (from reference)
#define N_G   60000
#define N_D   40000
#define NTOT  100000          // N_G + N_D
#define DIM   64
#define E_EDGES 1600000
#define B_BATCH 4096
#define K_NEG   1
#define DECAY_F 1e-4f
#define NB_SCAN ((NTOT + 1023) / 1024)   // 98 blocks for the hierarchical scan

// ---------------------------------------------------------------------------
// CSR build: histogram -> hierarchical scan (3 kernels) -> scatter (packed int2)
// (atomics here are spread over 100K addresses — uncontended, fine)
// ---------------------------------------------------------------------------
__global__ void k_count(const int* __restrict__ arow, int* __restrict__ cnt) {
    int e = blockIdx.x * blockDim.x + threadIdx.x;
    if (e >= E_EDGES) return;
    atomicAdd(&cnt[arow[e]], 1);
}

// scan1: per-block (1024 elems) exclusive scan of cnt -> row_ptr; block totals.
__global__ void k_scan1(const int* __restrict__ cnt, int* __restrict__ row_ptr,
                        int* __restrict__ blocksum) {
    int gid  = blockIdx.x * 1024 + threadIdx.x;
    int lane = threadIdx.x & 63;
    int wid  = threadIdx.x >> 6;           // 16 waves
    int v = (gid < NTOT) ? cnt[gid] : 0;
    int x = v;
    #pragma unroll
    for (int off = 1; off < 64; off <<= 1) {
        int y = __shfl_up(x, off);
        if (lane >= off) x += y;
    }
    __shared__ int wsum[16];
    if (lane == 63) wsum[wid] = x;
    __syncthreads();
    if (wid == 0) {
        int w = (lane < 16) ? wsum[lane] : 0;
        #pragma unroll
        for (int off = 1; off < 16; off <<= 1) {
            int y = __shfl_up(w, off);
            if (lane >= off) w += y;
        }
        if (lane < 16) wsum[lane] = w;     // inclusive wave-sum scan
    }
    __syncthreads();
    int woff = (wid == 0) ? 0 : wsum[wid - 1];
    int incl = x + woff;
    if (gid < NTOT) row_ptr[gid] = incl - v;   // block-local exclusive
    if (threadIdx.x == 1023) blocksum[blockIdx.x] = incl;
}

// scan2: exclusive scan of the 98 block sums (single small block, 2 waves).
__global__ void k_scan2(const int* __restrict__ blocksum, int* __restrict__ blockoff) {
    int t = threadIdx.x;                   // 0..127
    int lane = t & 63;
    int wid  = t >> 6;
    int v = (t < NB_SCAN) ? blocksum[t] : 0;
    int x = v;
    #pragma unroll
    for (int off = 1; off < 64; off <<= 1) {
        int y = __shfl_up(x, off);
        if (lane >= off) x += y;
    }
    __shared__ int wsum[2];
    if (lane == 63) wsum[wid] = x;
    __syncthreads();
    int incl = x + ((wid == 1) ? wsum[0] : 0);
    if (t < NB_SCAN) blockoff[t] = incl - v;
}

// scan3: add block offsets in place; mirror into cursor; set sentinel.
__global__ void k_scan3(int* __restrict__ row_ptr, const int* __restrict__ blockoff,
                        int* __restrict__ cursor) {
    int gid = blockIdx.x * blockDim.x + threadIdx.x;
    if (gid < NTOT) {
        int r = row_ptr[gid] + blockoff[gid >> 10];
        row_ptr[gid] = r;
        cursor[gid]  = r;
    }
    if (gid == 0) row_ptr[NTOT] = E_EDGES;
}

__global__ void k_scatter(const int* __restrict__ arow, const int* __restrict__ acol,
                          const float* __restrict__ aval, int* __restrict__ cursor,
                          int2* __restrict__ edge_s) {
    int e = blockIdx.x * blockDim.x + threadIdx.x;
    if (e >= E_EDGES) return;
    int r = arow[e];
    int pos = atomicAdd(&cursor[r], 1);
    edge_s[pos] = make_int2(acol[e], __float_as_int(aval[e]));
}

// ---------------------------------------------------------------------------
// Hop 1: side1[row] = sum val * raw[col]   (raw = concat(ge, de), read in place)
// One wave64 per row; lane l holds element l. Unroll x8; masked-batch tail so
// the remainder's gathers also issue in parallel (no serial dependent chain).
// ---------------------------------------------------------------------------
__global__ void spmm_first(const int* __restrict__ row_ptr, const int2* __restrict__ edge_s,
                           const float* __restrict__ ge, const float* __restrict__ de,
                           float* __restrict__ side1) {
    int gtid = blockIdx.x * blockDim.x + threadIdx.x;
    int row  = gtid >> 6;
    int lane = gtid & 63;
    if (row >= NTOT) return;
    int s = row_ptr[row];
    int e = row_ptr[row + 1];
    float acc0 = 0.0f, acc1 = 0.0f;
    for (; s + 8 <= e; s += 8) {
        int2 ed[8];
        #pragma unroll
        for (int i = 0; i < 8; ++i) ed[i] = edge_s[s + i];
        float a[8];
        #pragma unroll
        for (int i = 0; i < 8; ++i) {
            int c = ed[i].x;
            const float* base = (c < N_G) ? (ge + (size_t)c * DIM)
                                          : (de + (size_t)(c - N_G) * DIM);
            a[i] = base[lane];
        }
        #pragma unroll
        for (int i = 0; i < 8; i += 2) {
            acc0 = fmaf(__int_as_float(ed[i].y),     a[i],     acc0);
            acc1 = fmaf(__int_as_float(ed[i + 1].y), a[i + 1], acc1);
        }
    }
    if (s < e) {                                  // masked tail batch
        int2 ed[8];
        #pragma unroll
        for (int i = 0; i < 8; ++i)
            ed[i] = (s + i < e) ? edge_s[s + i] : make_int2(0, 0);
        float a[8];
        #pragma unroll
        for (int i = 0; i < 8; ++i) {
            int c = ed[i].x;
            const float* base = (c < N_G) ? (ge + (size_t)c * DIM)
                                          : (de + (size_t)(c - N_G) * DIM);
            a[i] = base[lane];
        }
        #pragma unroll
        for (int i = 0; i < 8; i += 2) {
            acc0 = fmaf(__int_as_float(ed[i].y),     a[i],     acc0);
            acc1 = fmaf(__int_as_float(ed[i + 1].y), a[i + 1], acc1);
        }
    }
    side1[(size_t)row * DIM + lane] = acc0 + acc1;
}

// ---------------------------------------------------------------------------
// Hop 2: side2[row] = sum val * side1[col]
// ---------------------------------------------------------------------------
__global__ void spmm_mid(const int* __restrict__ row_ptr, const int2* __restrict__ edge_s,
                         const float* __restrict__ src, float* __restrict__ dst) {
    int gtid = blockIdx.x * blockDim.x + threadIdx.x;
    int row  = gtid >> 6;
    int lane = gtid & 63;
    if (row >= NTOT) return;
    int s = row_ptr[row];
    int e = row_ptr[row + 1];
    float acc0 = 0.0f, acc1 = 0.0f;
    for (; s + 8 <= e; s += 8) {
        int2 ed[8];
        #pragma unroll
        for (int i = 0; i < 8; ++i) ed[i] = edge_s[s + i];
        float a[8];
        #pragma unroll
        for (int i = 0; i < 8; ++i) a[i] = src[(size_t)ed[i].x * DIM + lane];
        #pragma unroll
        for (int i = 0; i < 8; i += 2) {
            acc0 = fmaf(__int_as_float(ed[i].y),     a[i],     acc0);
            acc1 = fmaf(__int_as_float(ed[i + 1].y), a[i + 1], acc1);
        }
    }
    if (s < e) {                                  // masked tail batch
        int2 ed[8];
        #pragma unroll
        for (int i = 0; i < 8; ++i)
            ed[i] = (s + i < e) ? edge_s[s + i] : make_int2(0, 0);
        float a[8];
        #pragma unroll
        for (int i = 0; i < 8; ++i) a[i] = src[(size_t)ed[i].x * DIM + lane];
        #pragma unroll
        for (int i = 0; i < 8; i += 2) {
            acc0 = fmaf(__int_as_float(ed[i].y),     a[i],     acc0);
            acc1 = fmaf(__int_as_float(ed[i + 1].y), a[i + 1], acc1);
        }
    }
    dst[(size_t)row * DIM + lane] = acc0 + acc1;
}

// ---------------------------------------------------------------------------
// Hop-3 pull for a single row: sum val * src[col], unroll 8 + masked tail.
// ---------------------------------------------------------------------------
__device__ __forceinline__ float pull_row(const int* __restrict__ row_ptr,
                                          const int2* __restrict__ edge_s,
                                          const float* __restrict__ src,
                                          int row, int lane) {
    int s = row_ptr[row];
    int e = row_ptr[row + 1];
    float acc0 = 0.0f, acc1 = 0.0f;
    for (; s + 8 <= e; s += 8) {
        int2 ed[8];
        #pragma unroll
        for (int i = 0; i < 8; ++i) ed[i] = edge_s[s + i];
        float a[8];
        #pragma unroll
        for (int i = 0; i < 8; ++i) a[i] = src[(size_t)ed[i].x * DIM + lane];
        #pragma unroll
        for (int i = 0; i < 8; i += 2) {
            acc0 = fmaf(__int_as_float(ed[i].y),     a[i],     acc0);
            acc1 = fmaf(__int_as_float(ed[i + 1].y), a[i + 1], acc1);
        }
    }
    if (s < e) {
        int2 ed[8];
        #pragma unroll
        for (int i = 0; i < 8; ++i)
            ed[i] = (s + i < e) ? edge_s[s + i] : make_int2(0, 0);
        float a[8];
        #pragma unroll
        for (int i = 0; i < 8; ++i) a[i] = src[(size_t)ed[i].x * DIM + lane];
        #pragma unroll
        for (int i = 0; i < 8; i += 2) {
            acc0 = fmaf(__int_as_float(ed[i].y),     a[i],     acc0);
            acc1 = fmaf(__int_as_float(ed[i + 1].y), a[i + 1], acc1);
        }
    }
    return acc0 + acc1;
}

// ---------------------------------------------------------------------------
// mean_rows: one wave per (batch, row-type). 3*B waves. NO atomics:
// writes mean row to mrows and the wave-reduced hop-0 reg term to regbuf[wave].
// ---------------------------------------------------------------------------
__global__ void mean_rows(const float* __restrict__ side1, const float* __restrict__ side2,
                          const int* __restrict__ row_ptr, const int2* __restrict__ edge_s,
                          const float* __restrict__ ge, const float* __restrict__ de,
                          const float* __restrict__ gt, const float* __restrict__ dt,
                          const int* __restrict__ user, const int* __restrict__ pos,
                          const int* __restrict__ neg, float* __restrict__ mrows,
                          float* __restrict__ regbuf) {
    int gtid = blockIdx.x * blockDim.x + threadIdx.x;
    int wave = gtid >> 6;                  // 0 .. 3*B-1
    int lane = gtid & 63;
    if (wave >= 3 * B_BATCH) return;
    int b = wave / 3;
    int j = wave - 3 * b;                  // 0=user, 1=pos, 2=neg

    int   row;
    float t, e0;
    if (j == 0) {
        int u = user[b];
        row = u;  t = gt[u];  e0 = ge[(size_t)u * DIM + lane];
    } else {
        int d = (j == 1) ? pos[b] : neg[b * K_NEG];
        row = N_G + d;  t = dt[d];  e0 = de[(size_t)d * DIM + lane];
    }
    float w0 = expf(-t);
    float w1 = w0 * t;
    float w2 = w1 * t * 0.5f;
    float w3 = w1 * t * t * (1.0f / 6.0f);

    float s1 = side1[(size_t)row * DIM + lane];
    float s2 = side2[(size_t)row * DIM + lane];
    float s3 = pull_row(row_ptr, edge_s, side2, row, lane);
    float m  = 0.25f * (w0 * e0 + w1 * s1 + w2 * s2 + w3 * s3);
    mrows[(size_t)wave * DIM + lane] = m;

    // hop-0 regularization contribution for this row occurrence (plain store)
    float r0 = w0 * e0;
    float reg = r0 * r0;
    #pragma unroll
    for (int off = 32; off > 0; off >>= 1) reg += __shfl_down(reg, off);
    if (lane == 0) regbuf[wave] = reg;
}

// ---------------------------------------------------------------------------
// loss_dot: one wave per batch element; reads the 3 mean rows (L2-hot).
// NO atomics: writes per-batch mf term to mfbuf[b].
// ---------------------------------------------------------------------------
__global__ void loss_dot(const float* __restrict__ mrows, float* __restrict__ mfbuf) {
    int gtid = blockIdx.x * blockDim.x + threadIdx.x;
    int b    = gtid >> 6;
    int lane = gtid & 63;
    if (b >= B_BATCH) return;
    float gm = mrows[(size_t)(3 * b + 0) * DIM + lane];
    float pm = mrows[(size_t)(3 * b + 1) * DIM + lane];
    float nm = mrows[(size_t)(3 * b + 2) * DIM + lane];
    float dotp = gm * pm;
    float dotn = gm * nm;
    #pragma unroll
    for (int off = 32; off > 0; off >>= 1) {
        dotp += __shfl_down(dotp, off);
        dotn += __shfl_down(dotn, off);
    }
    if (lane == 0) {
        float x = dotn - dotp;
        mfbuf[b] = fmaxf(x, 0.0f) + log1pf(expf(-fabsf(x)));   // log1p(exp(x))
    }
}

// ---------------------------------------------------------------------------
// final_reduce: single block sums regbuf (3B) + mfbuf (B), emits 3 outputs.
// ---------------------------------------------------------------------------
__global__ void final_reduce(const float* __restrict__ regbuf,
                             const float* __restrict__ mfbuf,
                             float* __restrict__ out) {
    int t    = threadIdx.x;                // 1024 threads = 16 waves
    int lane = t & 63;
    int wid  = t >> 6;
    float mf = 0.0f, rg = 0.0f;
    for (int i = t; i < B_BATCH; i += 1024)     mf += mfbuf[i];
    for (int i = t; i < 3 * B_BATCH; i += 1024) rg += regbuf[i];
    #pragma unroll
    for (int off = 32; off > 0; off >>= 1) {
        mf += __shfl_down(mf, off);
        rg += __shfl_down(rg, off);
    }
    __shared__ float smf[16], srg[16];
    if (lane == 0) { smf[wid] = mf; srg[wid] = rg; }
    __syncthreads();
    if (t == 0) {
        float M = 0.0f, R = 0.0f;
        #pragma unroll
        for (int i = 0; i < 16; ++i) { M += smf[i]; R += srg[i]; }
        float mfm = M / (float)B_BATCH;
        float emb = DECAY_F * (R * 0.5f) / (float)B_BATCH;
        out[0] = mfm + emb;
        out[1] = mfm;
        out[2] = emb;
    }
}

extern "C" void kernel_launch(void* const* d_in, const int* in_sizes, int n_in,
                              void* d_out, int out_size, void* d_ws, size_t ws_size,
                              hipStream_t stream) {
    const float* ge   = (const float*)d_in[0];
    const float* de   = (const float*)d_in[1];
    const float* gt   = (const float*)d_in[2];
    const float* dt   = (const float*)d_in[3];
    const float* aval = (const float*)d_in[4];
    const int*   arow = (const int*)d_in[5];
    const int*   acol = (const int*)d_in[6];
    const int*   user = (const int*)d_in[7];
    const int*   pos  = (const int*)d_in[8];
    const int*   neg  = (const int*)d_in[9];
    float* out = (float*)d_out;

    // Workspace layout (~68.6 MB)
    char* ws = (char*)d_ws;
    const size_t bufBytes = (size_t)NTOT * DIM * sizeof(float);
    float* side1    = (float*)(ws);
    float* side2    = (float*)(ws + bufBytes);
    char*  p        = ws + 2 * bufBytes;
    int*   row_ptr  = (int*)p;             p += (NTOT + 1) * sizeof(int);
    int*   cnt      = (int*)p;             p += NTOT * sizeof(int);
    int*   cursor   = (int*)p;             p += NTOT * sizeof(int);
    int*   blocksum = (int*)p;             p += NB_SCAN * sizeof(int);
    int*   blockoff = (int*)p;             p += NB_SCAN * sizeof(int);
    int2*  edge_s   = (int2*)p;            p += (size_t)E_EDGES * sizeof(int2);
    float* mrows    = (float*)p;           p += (size_t)3 * B_BATCH * DIM * sizeof(float);
    float* regbuf   = (float*)p;           p += (size_t)3 * B_BATCH * sizeof(float);
    float* mfbuf    = (float*)p;

    hipMemsetAsync(cnt, 0, NTOT * sizeof(int), stream);

    // CSR build (reused by all hops)
    k_count <<<(E_EDGES + 255) / 256, 256, 0, stream>>>(arow, cnt);
    k_scan1 <<<NB_SCAN, 1024, 0, stream>>>(cnt, row_ptr, blocksum);
    k_scan2 <<<1, 128, 0, stream>>>(blocksum, blockoff);
    k_scan3 <<<(NTOT + 255) / 256, 256, 0, stream>>>(row_ptr, blockoff, cursor);
    k_scatter<<<(E_EDGES + 255) / 256, 256, 0, stream>>>(arow, acol, aval, cursor, edge_s);

    const int spmm_blocks = (NTOT * 64 + 255) / 256;
    spmm_first<<<spmm_blocks, 256, 0, stream>>>(row_ptr, edge_s, ge, de, side1);
    spmm_mid  <<<spmm_blocks, 256, 0, stream>>>(row_ptr, edge_s, side1, side2);

    mean_rows<<<(3 * B_BATCH * 64 + 255) / 256, 256, 0, stream>>>(
        side1, side2, row_ptr, edge_s, ge, de, gt, dt, user, pos, neg, mrows, regbuf);
    loss_dot<<<(B_BATCH * 64 + 255) / 256, 256, 0, stream>>>(mrows, mfbuf);
    final_reduce<<<1, 1024, 0, stream>>>(regbuf, mfbuf, out);
}

// Round 7
// 274.081 us; speedup vs baseline: 1.9994x; 1.2845x over previous
//
#include <hip/hip_runtime.h>
#include <math.h>

// Problem constants (from reference)
#define N_G   60000
#define N_D   40000
#define NTOT  100000          // N_G + N_D
#define DIM   64
#define E_EDGES 1600000
#define B_BATCH 4096
#define K_NEG   1
#define DECAY_F 1e-4f
#define NB_SCAN ((NTOT + 1023) / 1024)   // 98 blocks for the hierarchical scan

#define BIN_SHIFT 10
#define NBIN ((NTOT + 1023) >> BIN_SHIFT)   // 98 bins of 1024 rows
#define SCAT_BLOCKS 512
#define EPB (E_EDGES / SCAT_BLOCKS)         // 3125 edges per pass-B block

// bf16 helpers (storage-only; all math in fp32)
__device__ __forceinline__ float bf2f(unsigned short u) {
    return __uint_as_float(((unsigned)u) << 16);
}
__device__ __forceinline__ unsigned short f2bf(float f) {
    unsigned b = __float_as_uint(f);
    return (unsigned short)((b + 0x7FFFu + ((b >> 16) & 1u)) >> 16);
}

// ---------------------------------------------------------------------------
// conv_raw: rawh = bf16(concat(ge, de)). One thread per 4 floats.
// ---------------------------------------------------------------------------
__global__ void conv_raw(const float* __restrict__ ge, const float* __restrict__ de,
                         ushort4* __restrict__ rawh) {
    int idx = blockIdx.x * blockDim.x + threadIdx.x;   // float4 index
    if (idx >= NTOT * (DIM / 4)) return;
    float4 v = (idx < N_G * (DIM / 4)) ? ((const float4*)ge)[idx]
                                       : ((const float4*)de)[idx - N_G * (DIM / 4)];
    rawh[idx] = make_ushort4(f2bf(v.x), f2bf(v.y), f2bf(v.z), f2bf(v.w));
}

// ---------------------------------------------------------------------------
// CSR build: histogram -> hierarchical scan -> two-level binned scatter
// ---------------------------------------------------------------------------
__global__ void k_count(const int* __restrict__ arow, int* __restrict__ cnt) {
    int e = blockIdx.x * blockDim.x + threadIdx.x;
    if (e >= E_EDGES) return;
    atomicAdd(&cnt[arow[e]], 1);
}

__global__ void k_scan1(const int* __restrict__ cnt, int* __restrict__ row_ptr,
                        int* __restrict__ blocksum) {
    int gid  = blockIdx.x * 1024 + threadIdx.x;
    int lane = threadIdx.x & 63;
    int wid  = threadIdx.x >> 6;           // 16 waves
    int v = (gid < NTOT) ? cnt[gid] : 0;
    int x = v;
    #pragma unroll
    for (int off = 1; off < 64; off <<= 1) {
        int y = __shfl_up(x, off);
        if (lane >= off) x += y;
    }
    __shared__ int wsum[16];
    if (lane == 63) wsum[wid] = x;
    __syncthreads();
    if (wid == 0) {
        int w = (lane < 16) ? wsum[lane] : 0;
        #pragma unroll
        for (int off = 1; off < 16; off <<= 1) {
            int y = __shfl_up(w, off);
            if (lane >= off) w += y;
        }
        if (lane < 16) wsum[lane] = w;
    }
    __syncthreads();
    int woff = (wid == 0) ? 0 : wsum[wid - 1];
    int incl = x + woff;
    if (gid < NTOT) row_ptr[gid] = incl - v;
    if (threadIdx.x == 1023) blocksum[blockIdx.x] = incl;
}

__global__ void k_scan2(const int* __restrict__ blocksum, int* __restrict__ blockoff) {
    int t = threadIdx.x;                   // 0..127
    int lane = t & 63;
    int wid  = t >> 6;
    int v = (t < NB_SCAN) ? blocksum[t] : 0;
    int x = v;
    #pragma unroll
    for (int off = 1; off < 64; off <<= 1) {
        int y = __shfl_up(x, off);
        if (lane >= off) x += y;
    }
    __shared__ int wsum[2];
    if (lane == 63) wsum[wid] = x;
    __syncthreads();
    int incl = x + ((wid == 1) ? wsum[0] : 0);
    if (t < NB_SCAN) blockoff[t] = incl - v;
}

// scan3: finalize row_ptr; seed per-bin global cursors (padded 16 ints = 64B).
__global__ void k_scan3(int* __restrict__ row_ptr, const int* __restrict__ blockoff,
                        int* __restrict__ gcur) {
    int gid = blockIdx.x * blockDim.x + threadIdx.x;
    if (gid < NTOT) {
        int r = row_ptr[gid] + blockoff[gid >> 10];
        row_ptr[gid] = r;
        if ((gid & ((1 << BIN_SHIFT) - 1)) == 0) gcur[(gid >> BIN_SHIFT) * 16] = r;
    }
    if (gid == 0) row_ptr[NTOT] = E_EDGES;
}

// Pass B: bin edges by row>>10 into tmp. Per-(block,bin) chunks are contiguous
// and written by one block -> lines merge in its XCD L2. One padded global
// atomic per (block,bin) for chunk allocation.
__global__ void __launch_bounds__(256) k_binscatter(
        const int* __restrict__ arow, const int* __restrict__ acol,
        const float* __restrict__ aval, int* __restrict__ gcur,
        int2* __restrict__ tmp) {
    __shared__ int cnt[NBIN], base[NBIN], lcur[NBIN];
    int t = threadIdx.x;
    int s = blockIdx.x * EPB, e = s + EPB;
    for (int i = t; i < NBIN; i += 256) cnt[i] = 0;
    __syncthreads();
    for (int i = s + t; i < e; i += 256)
        atomicAdd(&cnt[arow[i] >> BIN_SHIFT], 1);
    __syncthreads();
    for (int i = t; i < NBIN; i += 256) {
        lcur[i] = 0;
        base[i] = (cnt[i] > 0) ? atomicAdd(&gcur[i * 16], cnt[i]) : 0;
    }
    __syncthreads();
    for (int i = s + t; i < e; i += 256) {
        int r   = arow[i];
        int bin = r >> BIN_SHIFT;
        int off = atomicAdd(&lcur[bin], 1);
        int drow = r & ((1 << BIN_SHIFT) - 1);
        tmp[base[bin] + off] = make_int2((drow << 17) | acol[i], __float_as_int(aval[i]));
    }
}

// Pass C: one block per bin; scatter within the bin's 1024-row window using
// LDS row cursors. Single block owns the window -> full-line evictions.
__global__ void __launch_bounds__(256) k_scatter2(
        const int* __restrict__ row_ptr, const int2* __restrict__ tmp,
        int2* __restrict__ edge_s) {
    __shared__ int cur[1 << BIN_SHIFT];
    int t = threadIdx.x;
    int rbase = blockIdx.x << BIN_SHIFT;
    for (int i = t; i < (1 << BIN_SHIFT); i += 256) {
        int idx = rbase + i;
        cur[i] = row_ptr[(idx < NTOT) ? idx : NTOT];
    }
    __syncthreads();
    int s = row_ptr[rbase];
    int rend = rbase + (1 << BIN_SHIFT); if (rend > NTOT) rend = NTOT;
    int e = row_ptr[rend];
    for (int i = s + t; i < e; i += 256) {
        int2 rec = tmp[i];
        int drow = ((unsigned)rec.x) >> 17;
        int pos  = atomicAdd(&cur[drow], 1);
        edge_s[pos] = make_int2(rec.x & 0x1FFFF, rec.y);
    }
}

// ---------------------------------------------------------------------------
// Hop 1: side1h[row] = bf16( sum val * rawh[col] ). One wave64 per row,
// lane l = element l (128B coalesced bf16 gather per edge). Unroll x8 +
// masked tail so remainder gathers also issue in parallel.
// ---------------------------------------------------------------------------
__global__ void spmm_first(const int* __restrict__ row_ptr, const int2* __restrict__ edge_s,
                           const unsigned short* __restrict__ rawh,
                           unsigned short* __restrict__ side1h) {
    int gtid = blockIdx.x * blockDim.x + threadIdx.x;
    int row  = gtid >> 6;
    int lane = gtid & 63;
    if (row >= NTOT) return;
    int s = row_ptr[row];
    int e = row_ptr[row + 1];
    float acc0 = 0.0f, acc1 = 0.0f;
    for (; s + 8 <= e; s += 8) {
        int2 ed[8];
        #pragma unroll
        for (int i = 0; i < 8; ++i) ed[i] = edge_s[s + i];
        float a[8];
        #pragma unroll
        for (int i = 0; i < 8; ++i) a[i] = bf2f(rawh[(size_t)ed[i].x * DIM + lane]);
        #pragma unroll
        for (int i = 0; i < 8; i += 2) {
            acc0 = fmaf(__int_as_float(ed[i].y),     a[i],     acc0);
            acc1 = fmaf(__int_as_float(ed[i + 1].y), a[i + 1], acc1);
        }
    }
    if (s < e) {                                  // masked tail batch
        int2 ed[8];
        #pragma unroll
        for (int i = 0; i < 8; ++i)
            ed[i] = (s + i < e) ? edge_s[s + i] : make_int2(0, 0);
        float a[8];
        #pragma unroll
        for (int i = 0; i < 8; ++i) a[i] = bf2f(rawh[(size_t)ed[i].x * DIM + lane]);
        #pragma unroll
        for (int i = 0; i < 8; i += 2) {
            acc0 = fmaf(__int_as_float(ed[i].y),     a[i],     acc0);
            acc1 = fmaf(__int_as_float(ed[i + 1].y), a[i + 1], acc1);
        }
    }
    side1h[(size_t)row * DIM + lane] = f2bf(acc0 + acc1);
}

// ---------------------------------------------------------------------------
// Hop 2: side2h[row] = bf16( sum val * side1h[col] )
// ---------------------------------------------------------------------------
__global__ void spmm_mid(const int* __restrict__ row_ptr, const int2* __restrict__ edge_s,
                         const unsigned short* __restrict__ src,
                         unsigned short* __restrict__ dst) {
    int gtid = blockIdx.x * blockDim.x + threadIdx.x;
    int row  = gtid >> 6;
    int lane = gtid & 63;
    if (row >= NTOT) return;
    int s = row_ptr[row];
    int e = row_ptr[row + 1];
    float acc0 = 0.0f, acc1 = 0.0f;
    for (; s + 8 <= e; s += 8) {
        int2 ed[8];
        #pragma unroll
        for (int i = 0; i < 8; ++i) ed[i] = edge_s[s + i];
        float a[8];
        #pragma unroll
        for (int i = 0; i < 8; ++i) a[i] = bf2f(src[(size_t)ed[i].x * DIM + lane]);
        #pragma unroll
        for (int i = 0; i < 8; i += 2) {
            acc0 = fmaf(__int_as_float(ed[i].y),     a[i],     acc0);
            acc1 = fmaf(__int_as_float(ed[i + 1].y), a[i + 1], acc1);
        }
    }
    if (s < e) {                                  // masked tail batch
        int2 ed[8];
        #pragma unroll
        for (int i = 0; i < 8; ++i)
            ed[i] = (s + i < e) ? edge_s[s + i] : make_int2(0, 0);
        float a[8];
        #pragma unroll
        for (int i = 0; i < 8; ++i) a[i] = bf2f(src[(size_t)ed[i].x * DIM + lane]);
        #pragma unroll
        for (int i = 0; i < 8; i += 2) {
            acc0 = fmaf(__int_as_float(ed[i].y),     a[i],     acc0);
            acc1 = fmaf(__int_as_float(ed[i + 1].y), a[i + 1], acc1);
        }
    }
    dst[(size_t)row * DIM + lane] = f2bf(acc0 + acc1);
}

// ---------------------------------------------------------------------------
// Hop-3 pull for one row over bf16 src: sum val * src[col]
// ---------------------------------------------------------------------------
__device__ __forceinline__ float pull_row_h(const int* __restrict__ row_ptr,
                                            const int2* __restrict__ edge_s,
                                            const unsigned short* __restrict__ src,
                                            int row, int lane) {
    int s = row_ptr[row];
    int e = row_ptr[row + 1];
    float acc0 = 0.0f, acc1 = 0.0f;
    for (; s + 8 <= e; s += 8) {
        int2 ed[8];
        #pragma unroll
        for (int i = 0; i < 8; ++i) ed[i] = edge_s[s + i];
        float a[8];
        #pragma unroll
        for (int i = 0; i < 8; ++i) a[i] = bf2f(src[(size_t)ed[i].x * DIM + lane]);
        #pragma unroll
        for (int i = 0; i < 8; i += 2) {
            acc0 = fmaf(__int_as_float(ed[i].y),     a[i],     acc0);
            acc1 = fmaf(__int_as_float(ed[i + 1].y), a[i + 1], acc1);
        }
    }
    if (s < e) {
        int2 ed[8];
        #pragma unroll
        for (int i = 0; i < 8; ++i)
            ed[i] = (s + i < e) ? edge_s[s + i] : make_int2(0, 0);
        float a[8];
        #pragma unroll
        for (int i = 0; i < 8; ++i) a[i] = bf2f(src[(size_t)ed[i].x * DIM + lane]);
        #pragma unroll
        for (int i = 0; i < 8; i += 2) {
            acc0 = fmaf(__int_as_float(ed[i].y),     a[i],     acc0);
            acc1 = fmaf(__int_as_float(ed[i + 1].y), a[i + 1], acc1);
        }
    }
    return acc0 + acc1;
}

// ---------------------------------------------------------------------------
// mean_rows: one wave per (batch, row-type). NO contended atomics.
// ---------------------------------------------------------------------------
__global__ void mean_rows(const unsigned short* __restrict__ side1h,
                          const unsigned short* __restrict__ side2h,
                          const int* __restrict__ row_ptr, const int2* __restrict__ edge_s,
                          const float* __restrict__ ge, const float* __restrict__ de,
                          const float* __restrict__ gt, const float* __restrict__ dt,
                          const int* __restrict__ user, const int* __restrict__ pos,
                          const int* __restrict__ neg, float* __restrict__ mrows,
                          float* __restrict__ regbuf) {
    int gtid = blockIdx.x * blockDim.x + threadIdx.x;
    int wave = gtid >> 6;                  // 0 .. 3*B-1
    int lane = gtid & 63;
    if (wave >= 3 * B_BATCH) return;
    int b = wave / 3;
    int j = wave - 3 * b;                  // 0=user, 1=pos, 2=neg

    int   row;
    float t, e0;
    if (j == 0) {
        int u = user[b];
        row = u;  t = gt[u];  e0 = ge[(size_t)u * DIM + lane];
    } else {
        int d = (j == 1) ? pos[b] : neg[b * K_NEG];
        row = N_G + d;  t = dt[d];  e0 = de[(size_t)d * DIM + lane];
    }
    float w0 = expf(-t);
    float w1 = w0 * t;
    float w2 = w1 * t * 0.5f;
    float w3 = w1 * t * t * (1.0f / 6.0f);

    float s1 = bf2f(side1h[(size_t)row * DIM + lane]);
    float s2 = bf2f(side2h[(size_t)row * DIM + lane]);
    float s3 = pull_row_h(row_ptr, edge_s, side2h, row, lane);
    float m  = 0.25f * (w0 * e0 + w1 * s1 + w2 * s2 + w3 * s3);
    mrows[(size_t)wave * DIM + lane] = m;

    float r0 = w0 * e0;
    float reg = r0 * r0;
    #pragma unroll
    for (int off = 32; off > 0; off >>= 1) reg += __shfl_down(reg, off);
    if (lane == 0) regbuf[wave] = reg;
}

// ---------------------------------------------------------------------------
// loss_dot: one wave per batch element; plain store of per-batch mf term.
// ---------------------------------------------------------------------------
__global__ void loss_dot(const float* __restrict__ mrows, float* __restrict__ mfbuf) {
    int gtid = blockIdx.x * blockDim.x + threadIdx.x;
    int b    = gtid >> 6;
    int lane = gtid & 63;
    if (b >= B_BATCH) return;
    float gm = mrows[(size_t)(3 * b + 0) * DIM + lane];
    float pm = mrows[(size_t)(3 * b + 1) * DIM + lane];
    float nm = mrows[(size_t)(3 * b + 2) * DIM + lane];
    float dotp = gm * pm;
    float dotn = gm * nm;
    #pragma unroll
    for (int off = 32; off > 0; off >>= 1) {
        dotp += __shfl_down(dotp, off);
        dotn += __shfl_down(dotn, off);
    }
    if (lane == 0) {
        float x = dotn - dotp;
        mfbuf[b] = fmaxf(x, 0.0f) + log1pf(expf(-fabsf(x)));   // log1p(exp(x))
    }
}

// ---------------------------------------------------------------------------
// final_reduce: single block sums regbuf (3B) + mfbuf (B), emits 3 outputs.
// ---------------------------------------------------------------------------
__global__ void final_reduce(const float* __restrict__ regbuf,
                             const float* __restrict__ mfbuf,
                             float* __restrict__ out) {
    int t    = threadIdx.x;                // 1024 threads = 16 waves
    int lane = t & 63;
    int wid  = t >> 6;
    float mf = 0.0f, rg = 0.0f;
    for (int i = t; i < B_BATCH; i += 1024)     mf += mfbuf[i];
    for (int i = t; i < 3 * B_BATCH; i += 1024) rg += regbuf[i];
    #pragma unroll
    for (int off = 32; off > 0; off >>= 1) {
        mf += __shfl_down(mf, off);
        rg += __shfl_down(rg, off);
    }
    __shared__ float smf[16], srg[16];
    if (lane == 0) { smf[wid] = mf; srg[wid] = rg; }
    __syncthreads();
    if (t == 0) {
        float M = 0.0f, R = 0.0f;
        #pragma unroll
        for (int i = 0; i < 16; ++i) { M += smf[i]; R += srg[i]; }
        float mfm = M / (float)B_BATCH;
        float emb = DECAY_F * (R * 0.5f) / (float)B_BATCH;
        out[0] = mfm + emb;
        out[1] = mfm;
        out[2] = emb;
    }
}

extern "C" void kernel_launch(void* const* d_in, const int* in_sizes, int n_in,
                              void* d_out, int out_size, void* d_ws, size_t ws_size,
                              hipStream_t stream) {
    const float* ge   = (const float*)d_in[0];
    const float* de   = (const float*)d_in[1];
    const float* gt   = (const float*)d_in[2];
    const float* dt   = (const float*)d_in[3];
    const float* aval = (const float*)d_in[4];
    const int*   arow = (const int*)d_in[5];
    const int*   acol = (const int*)d_in[6];
    const int*   user = (const int*)d_in[7];
    const int*   pos  = (const int*)d_in[8];
    const int*   neg  = (const int*)d_in[9];
    float* out = (float*)d_out;

    // Workspace layout (~68.3 MB)
    char* ws = (char*)d_ws;
    const size_t rowHBytes = (size_t)NTOT * DIM * sizeof(unsigned short);   // 12.8 MB
    unsigned short* rawh   = (unsigned short*)(ws);
    unsigned short* side1h = (unsigned short*)(ws + rowHBytes);
    unsigned short* side2h = (unsigned short*)(ws + 2 * rowHBytes);
    char* p = ws + 3 * rowHBytes;
    int2*  tmp     = (int2*)p;             p += (size_t)E_EDGES * sizeof(int2);
    int2*  edge_s  = (int2*)p;             p += (size_t)E_EDGES * sizeof(int2);
    float* mrows   = (float*)p;            p += (size_t)3 * B_BATCH * DIM * sizeof(float);
    int*   row_ptr = (int*)p;              p += (NTOT + 1) * sizeof(int);
    int*   cnt     = (int*)p;              p += NTOT * sizeof(int);
    int*   blocksum= (int*)p;              p += NB_SCAN * sizeof(int);
    int*   blockoff= (int*)p;              p += NB_SCAN * sizeof(int);
    int*   gcur    = (int*)p;              p += NBIN * 16 * sizeof(int);
    float* regbuf  = (float*)p;            p += (size_t)3 * B_BATCH * sizeof(float);
    float* mfbuf   = (float*)p;

    hipMemsetAsync(cnt, 0, NTOT * sizeof(int), stream);

    conv_raw<<<(NTOT * (DIM / 4) + 255) / 256, 256, 0, stream>>>(ge, de, (ushort4*)rawh);

    // CSR build
    k_count <<<(E_EDGES + 255) / 256, 256, 0, stream>>>(arow, cnt);
    k_scan1 <<<NB_SCAN, 1024, 0, stream>>>(cnt, row_ptr, blocksum);
    k_scan2 <<<1, 128, 0, stream>>>(blocksum, blockoff);
    k_scan3 <<<(NTOT + 255) / 256, 256, 0, stream>>>(row_ptr, blockoff, gcur);
    k_binscatter<<<SCAT_BLOCKS, 256, 0, stream>>>(arow, acol, aval, gcur, tmp);
    k_scatter2  <<<NBIN, 256, 0, stream>>>(row_ptr, tmp, edge_s);

    const int spmm_blocks = (NTOT * 64 + 255) / 256;
    spmm_first<<<spmm_blocks, 256, 0, stream>>>(row_ptr, edge_s, rawh, side1h);
    spmm_mid  <<<spmm_blocks, 256, 0, stream>>>(row_ptr, edge_s, side1h, side2h);

    mean_rows<<<(3 * B_BATCH * 64 + 255) / 256, 256, 0, stream>>>(
        side1h, side2h, row_ptr, edge_s, ge, de, gt, dt, user, pos, neg, mrows, regbuf);
    loss_dot<<<(B_BATCH * 64 + 255) / 256, 256, 0, stream>>>(mrows, mfbuf);
    final_reduce<<<1, 1024, 0, stream>>>(regbuf, mfbuf, out);
}

// Round 8
// 208.960 us; speedup vs baseline: 2.6226x; 1.3116x over previous
//
#include <hip/hip_runtime.h>
#include <math.h>

// Problem constants (from reference)
#define N_G   60000
#define N_D   40000
#define NTOT  100000          // N_G + N_D
#define DIM   64
#define E_EDGES 1600000
#define B_BATCH 4096
#define K_NEG   1
#define DECAY_F 1e-4f

#define BIN_SHIFT 10
#define BIN_SIZE (1 << BIN_SHIFT)
#define NBIN ((NTOT + BIN_SIZE - 1) >> BIN_SHIFT)   // 98 bins of 1024 rows
#define SCAT_BLOCKS 512
#define EPB (E_EDGES / SCAT_BLOCKS)                 // 3125 edges per block
#define NBB (NBIN * SCAT_BLOCKS)                    // 50176 (block,bin) counters
#define NB2 ((NBB + 1023) / 1024)                   // 49 scan blocks

// bf16 helpers (storage-only; all math in fp32)
__device__ __forceinline__ float bf2f(unsigned short u) {
    return __uint_as_float(((unsigned)u) << 16);
}
__device__ __forceinline__ unsigned short f2bf(float f) {
    unsigned b = __float_as_uint(f);
    return (unsigned short)((b + 0x7FFFu + ((b >> 16) & 1u)) >> 16);
}

// ---------------------------------------------------------------------------
// conv_raw: rawh = bf16(concat(ge, de)). One thread per 4 floats.
// ---------------------------------------------------------------------------
__global__ void conv_raw(const float* __restrict__ ge, const float* __restrict__ de,
                         ushort4* __restrict__ rawh) {
    int idx = blockIdx.x * blockDim.x + threadIdx.x;   // float4 index
    if (idx >= NTOT * (DIM / 4)) return;
    float4 v = (idx < N_G * (DIM / 4)) ? ((const float4*)ge)[idx]
                                       : ((const float4*)de)[idx - N_G * (DIM / 4)];
    rawh[idx] = make_ushort4(f2bf(v.x), f2bf(v.y), f2bf(v.z), f2bf(v.w));
}

// ---------------------------------------------------------------------------
// CSR build v3 — zero global atomics.
// hist1 -> scan(bbcnt) -> binscatter -> binfinal
// ---------------------------------------------------------------------------

// Per-block LDS histogram over the 98 bins; plain stores to bbcnt[bin][block].
__global__ void __launch_bounds__(256) k_hist1(const int* __restrict__ arow,
                                               int* __restrict__ bbcnt) {
    __shared__ int cnt[NBIN];
    int t = threadIdx.x;
    for (int i = t; i < NBIN; i += 256) cnt[i] = 0;
    __syncthreads();
    int s = blockIdx.x * EPB, e = s + EPB;
    for (int i = s + t; i < e; i += 256)
        atomicAdd(&cnt[arow[i] >> BIN_SHIFT], 1);    // LDS atomic
    __syncthreads();
    for (int i = t; i < NBIN; i += 256)
        bbcnt[i * SCAT_BLOCKS + blockIdx.x] = cnt[i];
}

// Hierarchical exclusive scan over NBB entries (bin-major) -> bbbase.
__global__ void k_scan1g(const int* __restrict__ in, int* __restrict__ excl,
                         int* __restrict__ blocksum) {
    int gid  = blockIdx.x * 1024 + threadIdx.x;
    int lane = threadIdx.x & 63;
    int wid  = threadIdx.x >> 6;           // 16 waves
    int v = (gid < NBB) ? in[gid] : 0;
    int x = v;
    #pragma unroll
    for (int off = 1; off < 64; off <<= 1) {
        int y = __shfl_up(x, off);
        if (lane >= off) x += y;
    }
    __shared__ int wsum[16];
    if (lane == 63) wsum[wid] = x;
    __syncthreads();
    if (wid == 0) {
        int w = (lane < 16) ? wsum[lane] : 0;
        #pragma unroll
        for (int off = 1; off < 16; off <<= 1) {
            int y = __shfl_up(w, off);
            if (lane >= off) w += y;
        }
        if (lane < 16) wsum[lane] = w;
    }
    __syncthreads();
    int woff = (wid == 0) ? 0 : wsum[wid - 1];
    int incl = x + woff;
    if (gid < NBB) excl[gid] = incl - v;
    if (threadIdx.x == 1023) blocksum[blockIdx.x] = incl;
}

__global__ void k_scan2g(const int* __restrict__ blocksum, int* __restrict__ blockoff) {
    int t = threadIdx.x;                   // 0..63 (NB2=49 fits one wave)
    int v = (t < NB2) ? blocksum[t] : 0;
    int x = v;
    #pragma unroll
    for (int off = 1; off < 64; off <<= 1) {
        int y = __shfl_up(x, off);
        if (t >= off) x += y;
    }
    if (t < NB2) blockoff[t] = x - v;
}

__global__ void k_scan3g(int* __restrict__ excl, const int* __restrict__ blockoff) {
    int gid = blockIdx.x * blockDim.x + threadIdx.x;
    if (gid < NBB) excl[gid] += blockoff[gid >> 10];
}

// Bin edges into tmp at FINAL positions (cursor base from bbbase; LDS atomics).
__global__ void __launch_bounds__(256) k_binscatter(
        const int* __restrict__ arow, const int* __restrict__ acol,
        const float* __restrict__ aval, const int* __restrict__ bbbase,
        int2* __restrict__ tmp) {
    __shared__ int lcur[NBIN];
    int t = threadIdx.x;
    for (int i = t; i < NBIN; i += 256)
        lcur[i] = bbbase[i * SCAT_BLOCKS + blockIdx.x];
    __syncthreads();
    int s = blockIdx.x * EPB, e = s + EPB;
    for (int i = s + t; i < e; i += 256) {
        int r   = arow[i];
        int bin = r >> BIN_SHIFT;
        int off = atomicAdd(&lcur[bin], 1);          // LDS atomic
        int drow = r & (BIN_SIZE - 1);
        tmp[off] = make_int2((drow << 17) | acol[i], __float_as_int(aval[i]));
    }
}

// Per bin: LDS row-histogram + local scan -> row_ptr (coalesced) + final scatter.
__global__ void __launch_bounds__(256) k_binfinal(
        const int* __restrict__ bbbase, const int2* __restrict__ tmp,
        int* __restrict__ row_ptr, int2* __restrict__ edge_s) {
    __shared__ int hist[BIN_SIZE];                   // then reused as cursors
    __shared__ int wsum[4];
    int t = threadIdx.x;
    int bin = blockIdx.x;
    int rbase = bin << BIN_SHIFT;
    int binstart = bbbase[bin * SCAT_BLOCKS];
    int binend   = (bin + 1 < NBIN) ? bbbase[(bin + 1) * SCAT_BLOCKS] : E_EDGES;

    for (int i = t; i < BIN_SIZE; i += 256) hist[i] = 0;
    __syncthreads();
    for (int i = binstart + t; i < binend; i += 256)
        atomicAdd(&hist[((unsigned)tmp[i].x) >> 17], 1);   // LDS atomic
    __syncthreads();

    // 256-thread exclusive scan of hist[1024]: each thread owns 4 elements.
    int lane = t & 63, wid = t >> 6;
    int b4 = t * 4;
    int h0 = hist[b4], h1 = hist[b4 + 1], h2 = hist[b4 + 2], h3 = hist[b4 + 3];
    int tsum = h0 + h1 + h2 + h3;
    int x = tsum;
    #pragma unroll
    for (int off = 1; off < 64; off <<= 1) {
        int y = __shfl_up(x, off);
        if (lane >= off) x += y;
    }
    if (lane == 63) wsum[wid] = x;
    __syncthreads();
    int woff = 0;
    #pragma unroll
    for (int i = 0; i < 4; ++i) if (i < wid) woff += wsum[i];
    int excl = woff + x - tsum;                      // exclusive prefix of thread's group

    int c0 = binstart + excl;
    int c1 = c0 + h0;
    int c2 = c1 + h1;
    int c3 = c2 + h2;
    __syncthreads();                                 // done reading hist as counts
    hist[b4] = c0; hist[b4 + 1] = c1; hist[b4 + 2] = c2; hist[b4 + 3] = c3;
    if (rbase + b4 + 3 < NTOT) {
        row_ptr[rbase + b4]     = c0;
        row_ptr[rbase + b4 + 1] = c1;
        row_ptr[rbase + b4 + 2] = c2;
        row_ptr[rbase + b4 + 3] = c3;
    } else {
        if (rbase + b4     < NTOT) row_ptr[rbase + b4]     = c0;
        if (rbase + b4 + 1 < NTOT) row_ptr[rbase + b4 + 1] = c1;
        if (rbase + b4 + 2 < NTOT) row_ptr[rbase + b4 + 2] = c2;
        if (rbase + b4 + 3 < NTOT) row_ptr[rbase + b4 + 3] = c3;
    }
    if (bin == NBIN - 1 && t == 0) row_ptr[NTOT] = E_EDGES;
    __syncthreads();

    for (int i = binstart + t; i < binend; i += 256) {
        int2 rec = tmp[i];
        int drow = ((unsigned)rec.x) >> 17;
        int pos  = atomicAdd(&hist[drow], 1);        // LDS atomic
        edge_s[pos] = make_int2(rec.x & 0x1FFFF, rec.y);
    }
}

// ---------------------------------------------------------------------------
// Hop 1: side1h[row] = bf16( sum val * rawh[col] ). One wave64 per row,
// lane l = element l (128B coalesced bf16 gather per edge). Unroll x8 +
// masked tail so remainder gathers also issue in parallel.
// ---------------------------------------------------------------------------
__global__ void spmm_first(const int* __restrict__ row_ptr, const int2* __restrict__ edge_s,
                           const unsigned short* __restrict__ rawh,
                           unsigned short* __restrict__ side1h) {
    int gtid = blockIdx.x * blockDim.x + threadIdx.x;
    int row  = gtid >> 6;
    int lane = gtid & 63;
    if (row >= NTOT) return;
    int s = row_ptr[row];
    int e = row_ptr[row + 1];
    float acc0 = 0.0f, acc1 = 0.0f;
    for (; s + 8 <= e; s += 8) {
        int2 ed[8];
        #pragma unroll
        for (int i = 0; i < 8; ++i) ed[i] = edge_s[s + i];
        float a[8];
        #pragma unroll
        for (int i = 0; i < 8; ++i) a[i] = bf2f(rawh[(size_t)ed[i].x * DIM + lane]);
        #pragma unroll
        for (int i = 0; i < 8; i += 2) {
            acc0 = fmaf(__int_as_float(ed[i].y),     a[i],     acc0);
            acc1 = fmaf(__int_as_float(ed[i + 1].y), a[i + 1], acc1);
        }
    }
    if (s < e) {                                  // masked tail batch
        int2 ed[8];
        #pragma unroll
        for (int i = 0; i < 8; ++i)
            ed[i] = (s + i < e) ? edge_s[s + i] : make_int2(0, 0);
        float a[8];
        #pragma unroll
        for (int i = 0; i < 8; ++i) a[i] = bf2f(rawh[(size_t)ed[i].x * DIM + lane]);
        #pragma unroll
        for (int i = 0; i < 8; i += 2) {
            acc0 = fmaf(__int_as_float(ed[i].y),     a[i],     acc0);
            acc1 = fmaf(__int_as_float(ed[i + 1].y), a[i + 1], acc1);
        }
    }
    side1h[(size_t)row * DIM + lane] = f2bf(acc0 + acc1);
}

// ---------------------------------------------------------------------------
// Hop 2: side2h[row] = bf16( sum val * side1h[col] )
// ---------------------------------------------------------------------------
__global__ void spmm_mid(const int* __restrict__ row_ptr, const int2* __restrict__ edge_s,
                         const unsigned short* __restrict__ src,
                         unsigned short* __restrict__ dst) {
    int gtid = blockIdx.x * blockDim.x + threadIdx.x;
    int row  = gtid >> 6;
    int lane = gtid & 63;
    if (row >= NTOT) return;
    int s = row_ptr[row];
    int e = row_ptr[row + 1];
    float acc0 = 0.0f, acc1 = 0.0f;
    for (; s + 8 <= e; s += 8) {
        int2 ed[8];
        #pragma unroll
        for (int i = 0; i < 8; ++i) ed[i] = edge_s[s + i];
        float a[8];
        #pragma unroll
        for (int i = 0; i < 8; ++i) a[i] = bf2f(src[(size_t)ed[i].x * DIM + lane]);
        #pragma unroll
        for (int i = 0; i < 8; i += 2) {
            acc0 = fmaf(__int_as_float(ed[i].y),     a[i],     acc0);
            acc1 = fmaf(__int_as_float(ed[i + 1].y), a[i + 1], acc1);
        }
    }
    if (s < e) {                                  // masked tail batch
        int2 ed[8];
        #pragma unroll
        for (int i = 0; i < 8; ++i)
            ed[i] = (s + i < e) ? edge_s[s + i] : make_int2(0, 0);
        float a[8];
        #pragma unroll
        for (int i = 0; i < 8; ++i) a[i] = bf2f(src[(size_t)ed[i].x * DIM + lane]);
        #pragma unroll
        for (int i = 0; i < 8; i += 2) {
            acc0 = fmaf(__int_as_float(ed[i].y),     a[i],     acc0);
            acc1 = fmaf(__int_as_float(ed[i + 1].y), a[i + 1], acc1);
        }
    }
    dst[(size_t)row * DIM + lane] = f2bf(acc0 + acc1);
}

// ---------------------------------------------------------------------------
// Hop-3 pull for one row over bf16 src: sum val * src[col]
// ---------------------------------------------------------------------------
__device__ __forceinline__ float pull_row_h(const int* __restrict__ row_ptr,
                                            const int2* __restrict__ edge_s,
                                            const unsigned short* __restrict__ src,
                                            int row, int lane) {
    int s = row_ptr[row];
    int e = row_ptr[row + 1];
    float acc0 = 0.0f, acc1 = 0.0f;
    for (; s + 8 <= e; s += 8) {
        int2 ed[8];
        #pragma unroll
        for (int i = 0; i < 8; ++i) ed[i] = edge_s[s + i];
        float a[8];
        #pragma unroll
        for (int i = 0; i < 8; ++i) a[i] = bf2f(src[(size_t)ed[i].x * DIM + lane]);
        #pragma unroll
        for (int i = 0; i < 8; i += 2) {
            acc0 = fmaf(__int_as_float(ed[i].y),     a[i],     acc0);
            acc1 = fmaf(__int_as_float(ed[i + 1].y), a[i + 1], acc1);
        }
    }
    if (s < e) {
        int2 ed[8];
        #pragma unroll
        for (int i = 0; i < 8; ++i)
            ed[i] = (s + i < e) ? edge_s[s + i] : make_int2(0, 0);
        float a[8];
        #pragma unroll
        for (int i = 0; i < 8; ++i) a[i] = bf2f(src[(size_t)ed[i].x * DIM + lane]);
        #pragma unroll
        for (int i = 0; i < 8; i += 2) {
            acc0 = fmaf(__int_as_float(ed[i].y),     a[i],     acc0);
            acc1 = fmaf(__int_as_float(ed[i + 1].y), a[i + 1], acc1);
        }
    }
    return acc0 + acc1;
}

// ---------------------------------------------------------------------------
// mean_rows: one wave per (batch, row-type). NO contended atomics.
// ---------------------------------------------------------------------------
__global__ void mean_rows(const unsigned short* __restrict__ side1h,
                          const unsigned short* __restrict__ side2h,
                          const int* __restrict__ row_ptr, const int2* __restrict__ edge_s,
                          const float* __restrict__ ge, const float* __restrict__ de,
                          const float* __restrict__ gt, const float* __restrict__ dt,
                          const int* __restrict__ user, const int* __restrict__ pos,
                          const int* __restrict__ neg, float* __restrict__ mrows,
                          float* __restrict__ regbuf) {
    int gtid = blockIdx.x * blockDim.x + threadIdx.x;
    int wave = gtid >> 6;                  // 0 .. 3*B-1
    int lane = gtid & 63;
    if (wave >= 3 * B_BATCH) return;
    int b = wave / 3;
    int j = wave - 3 * b;                  // 0=user, 1=pos, 2=neg

    int   row;
    float t, e0;
    if (j == 0) {
        int u = user[b];
        row = u;  t = gt[u];  e0 = ge[(size_t)u * DIM + lane];
    } else {
        int d = (j == 1) ? pos[b] : neg[b * K_NEG];
        row = N_G + d;  t = dt[d];  e0 = de[(size_t)d * DIM + lane];
    }
    float w0 = expf(-t);
    float w1 = w0 * t;
    float w2 = w1 * t * 0.5f;
    float w3 = w1 * t * t * (1.0f / 6.0f);

    float s1 = bf2f(side1h[(size_t)row * DIM + lane]);
    float s2 = bf2f(side2h[(size_t)row * DIM + lane]);
    float s3 = pull_row_h(row_ptr, edge_s, side2h, row, lane);
    float m  = 0.25f * (w0 * e0 + w1 * s1 + w2 * s2 + w3 * s3);
    mrows[(size_t)wave * DIM + lane] = m;

    float r0 = w0 * e0;
    float reg = r0 * r0;
    #pragma unroll
    for (int off = 32; off > 0; off >>= 1) reg += __shfl_down(reg, off);
    if (lane == 0) regbuf[wave] = reg;
}

// ---------------------------------------------------------------------------
// loss_dot: one wave per batch element; plain store of per-batch mf term.
// ---------------------------------------------------------------------------
__global__ void loss_dot(const float* __restrict__ mrows, float* __restrict__ mfbuf) {
    int gtid = blockIdx.x * blockDim.x + threadIdx.x;
    int b    = gtid >> 6;
    int lane = gtid & 63;
    if (b >= B_BATCH) return;
    float gm = mrows[(size_t)(3 * b + 0) * DIM + lane];
    float pm = mrows[(size_t)(3 * b + 1) * DIM + lane];
    float nm = mrows[(size_t)(3 * b + 2) * DIM + lane];
    float dotp = gm * pm;
    float dotn = gm * nm;
    #pragma unroll
    for (int off = 32; off > 0; off >>= 1) {
        dotp += __shfl_down(dotp, off);
        dotn += __shfl_down(dotn, off);
    }
    if (lane == 0) {
        float x = dotn - dotp;
        mfbuf[b] = fmaxf(x, 0.0f) + log1pf(expf(-fabsf(x)));   // log1p(exp(x))
    }
}

// ---------------------------------------------------------------------------
// final_reduce: single block sums regbuf (3B) + mfbuf (B), emits 3 outputs.
// ---------------------------------------------------------------------------
__global__ void final_reduce(const float* __restrict__ regbuf,
                             const float* __restrict__ mfbuf,
                             float* __restrict__ out) {
    int t    = threadIdx.x;                // 1024 threads = 16 waves
    int lane = t & 63;
    int wid  = t >> 6;
    float mf = 0.0f, rg = 0.0f;
    for (int i = t; i < B_BATCH; i += 1024)     mf += mfbuf[i];
    for (int i = t; i < 3 * B_BATCH; i += 1024) rg += regbuf[i];
    #pragma unroll
    for (int off = 32; off > 0; off >>= 1) {
        mf += __shfl_down(mf, off);
        rg += __shfl_down(rg, off);
    }
    __shared__ float smf[16], srg[16];
    if (lane == 0) { smf[wid] = mf; srg[wid] = rg; }
    __syncthreads();
    if (t == 0) {
        float M = 0.0f, R = 0.0f;
        #pragma unroll
        for (int i = 0; i < 16; ++i) { M += smf[i]; R += srg[i]; }
        float mfm = M / (float)B_BATCH;
        float emb = DECAY_F * (R * 0.5f) / (float)B_BATCH;
        out[0] = mfm + emb;
        out[1] = mfm;
        out[2] = emb;
    }
}

extern "C" void kernel_launch(void* const* d_in, const int* in_sizes, int n_in,
                              void* d_out, int out_size, void* d_ws, size_t ws_size,
                              hipStream_t stream) {
    const float* ge   = (const float*)d_in[0];
    const float* de   = (const float*)d_in[1];
    const float* gt   = (const float*)d_in[2];
    const float* dt   = (const float*)d_in[3];
    const float* aval = (const float*)d_in[4];
    const int*   arow = (const int*)d_in[5];
    const int*   acol = (const int*)d_in[6];
    const int*   user = (const int*)d_in[7];
    const int*   pos  = (const int*)d_in[8];
    const int*   neg  = (const int*)d_in[9];
    float* out = (float*)d_out;

    // Workspace layout (~68 MB)
    char* ws = (char*)d_ws;
    const size_t rowHBytes = (size_t)NTOT * DIM * sizeof(unsigned short);   // 12.8 MB
    unsigned short* rawh   = (unsigned short*)(ws);
    unsigned short* side1h = (unsigned short*)(ws + rowHBytes);
    unsigned short* side2h = (unsigned short*)(ws + 2 * rowHBytes);
    char* p = ws + 3 * rowHBytes;
    int2*  tmp     = (int2*)p;             p += (size_t)E_EDGES * sizeof(int2);
    int2*  edge_s  = (int2*)p;             p += (size_t)E_EDGES * sizeof(int2);
    float* mrows   = (float*)p;            p += (size_t)3 * B_BATCH * DIM * sizeof(float);
    int*   row_ptr = (int*)p;              p += (NTOT + 1) * sizeof(int);
    int*   bbcnt   = (int*)p;              p += (size_t)NBB * sizeof(int);
    int*   bbbase  = (int*)p;              p += (size_t)NBB * sizeof(int);
    int*   blocksum= (int*)p;              p += 64 * sizeof(int);
    int*   blockoff= (int*)p;              p += 64 * sizeof(int);
    float* regbuf  = (float*)p;            p += (size_t)3 * B_BATCH * sizeof(float);
    float* mfbuf   = (float*)p;

    conv_raw<<<(NTOT * (DIM / 4) + 255) / 256, 256, 0, stream>>>(ge, de, (ushort4*)rawh);

    // CSR build — no global atomics anywhere.
    k_hist1     <<<SCAT_BLOCKS, 256, 0, stream>>>(arow, bbcnt);
    k_scan1g    <<<NB2, 1024, 0, stream>>>(bbcnt, bbbase, blocksum);
    k_scan2g    <<<1, 64, 0, stream>>>(blocksum, blockoff);
    k_scan3g    <<<(NBB + 255) / 256, 256, 0, stream>>>(bbbase, blockoff);
    k_binscatter<<<SCAT_BLOCKS, 256, 0, stream>>>(arow, acol, aval, bbbase, tmp);
    k_binfinal  <<<NBIN, 256, 0, stream>>>(bbbase, tmp, row_ptr, edge_s);

    const int spmm_blocks = (NTOT * 64 + 255) / 256;
    spmm_first<<<spmm_blocks, 256, 0, stream>>>(row_ptr, edge_s, rawh, side1h);
    spmm_mid  <<<spmm_blocks, 256, 0, stream>>>(row_ptr, edge_s, side1h, side2h);

    mean_rows<<<(3 * B_BATCH * 64 + 255) / 256, 256, 0, stream>>>(
        side1h, side2h, row_ptr, edge_s, ge, de, gt, dt, user, pos, neg, mrows, regbuf);
    loss_dot<<<(B_BATCH * 64 + 255) / 256, 256, 0, stream>>>(mrows, mfbuf);
    final_reduce<<<1, 1024, 0, stream>>>(regbuf, mfbuf, out);
}

// Round 9
// 183.834 us; speedup vs baseline: 2.9810x; 1.1367x over previous
//
#include <hip/hip_runtime.h>
#include <math.h>

// Problem constants (from reference)
#define N_G   60000
#define N_D   40000
#define NTOT  100000          // N_G + N_D
#define DIM   64
#define E_EDGES 1600000
#define B_BATCH 4096
#define K_NEG   1
#define DECAY_F 1e-4f

#define BIN_SHIFT 10
#define BIN_SIZE (1 << BIN_SHIFT)
#define NBIN ((NTOT + BIN_SIZE - 1) >> BIN_SHIFT)   // 98 bins of 1024 rows
#define SCAT_BLOCKS 512
#define EPB (E_EDGES / SCAT_BLOCKS)                 // 3125 edges per block
#define NBB (NBIN * SCAT_BLOCKS)                    // 50176 (block,bin) counters
#define NB2 ((NBB + 1023) / 1024)                   // 49 scan blocks

// bf16 helpers (storage-only; all math in fp32)
__device__ __forceinline__ float bf2f(unsigned short u) {
    return __uint_as_float(((unsigned)u) << 16);
}
__device__ __forceinline__ unsigned short f2bf(float f) {
    unsigned b = __float_as_uint(f);
    return (unsigned short)((b + 0x7FFFu + ((b >> 16) & 1u)) >> 16);
}
// packed-pair unpack: dword holds [lo: elem 2k][hi: elem 2k+1]
__device__ __forceinline__ float bflo(unsigned u) { return __uint_as_float(u << 16); }
__device__ __forceinline__ float bfhi(unsigned u) { return __uint_as_float(u & 0xFFFF0000u); }

// ---------------------------------------------------------------------------
// conv_raw: rawh = bf16(concat(ge, de)). One thread per 4 floats.
// ---------------------------------------------------------------------------
__global__ void conv_raw(const float* __restrict__ ge, const float* __restrict__ de,
                         ushort4* __restrict__ rawh) {
    int idx = blockIdx.x * blockDim.x + threadIdx.x;   // float4 index
    if (idx >= NTOT * (DIM / 4)) return;
    float4 v = (idx < N_G * (DIM / 4)) ? ((const float4*)ge)[idx]
                                       : ((const float4*)de)[idx - N_G * (DIM / 4)];
    rawh[idx] = make_ushort4(f2bf(v.x), f2bf(v.y), f2bf(v.z), f2bf(v.w));
}

// ---------------------------------------------------------------------------
// CSR build — zero global atomics. hist1 -> scan(bbcnt) -> binscatter -> binfinal
// ---------------------------------------------------------------------------
__global__ void __launch_bounds__(256) k_hist1(const int* __restrict__ arow,
                                               int* __restrict__ bbcnt) {
    __shared__ int cnt[NBIN];
    int t = threadIdx.x;
    for (int i = t; i < NBIN; i += 256) cnt[i] = 0;
    __syncthreads();
    int s = blockIdx.x * EPB, e = s + EPB;
    for (int i = s + t; i < e; i += 256)
        atomicAdd(&cnt[arow[i] >> BIN_SHIFT], 1);    // LDS atomic
    __syncthreads();
    for (int i = t; i < NBIN; i += 256)
        bbcnt[i * SCAT_BLOCKS + blockIdx.x] = cnt[i];
}

__global__ void k_scan1g(const int* __restrict__ in, int* __restrict__ excl,
                         int* __restrict__ blocksum) {
    int gid  = blockIdx.x * 1024 + threadIdx.x;
    int lane = threadIdx.x & 63;
    int wid  = threadIdx.x >> 6;           // 16 waves
    int v = (gid < NBB) ? in[gid] : 0;
    int x = v;
    #pragma unroll
    for (int off = 1; off < 64; off <<= 1) {
        int y = __shfl_up(x, off);
        if (lane >= off) x += y;
    }
    __shared__ int wsum[16];
    if (lane == 63) wsum[wid] = x;
    __syncthreads();
    if (wid == 0) {
        int w = (lane < 16) ? wsum[lane] : 0;
        #pragma unroll
        for (int off = 1; off < 16; off <<= 1) {
            int y = __shfl_up(w, off);
            if (lane >= off) w += y;
        }
        if (lane < 16) wsum[lane] = w;
    }
    __syncthreads();
    int woff = (wid == 0) ? 0 : wsum[wid - 1];
    int incl = x + woff;
    if (gid < NBB) excl[gid] = incl - v;
    if (threadIdx.x == 1023) blocksum[blockIdx.x] = incl;
}

__global__ void k_scan2g(const int* __restrict__ blocksum, int* __restrict__ blockoff) {
    int t = threadIdx.x;                   // 0..63 (NB2=49 fits one wave)
    int v = (t < NB2) ? blocksum[t] : 0;
    int x = v;
    #pragma unroll
    for (int off = 1; off < 64; off <<= 1) {
        int y = __shfl_up(x, off);
        if (t >= off) x += y;
    }
    if (t < NB2) blockoff[t] = x - v;
}

__global__ void k_scan3g(int* __restrict__ excl, const int* __restrict__ blockoff) {
    int gid = blockIdx.x * blockDim.x + threadIdx.x;
    if (gid < NBB) excl[gid] += blockoff[gid >> 10];
}

__global__ void __launch_bounds__(256) k_binscatter(
        const int* __restrict__ arow, const int* __restrict__ acol,
        const float* __restrict__ aval, const int* __restrict__ bbbase,
        int2* __restrict__ tmp) {
    __shared__ int lcur[NBIN];
    int t = threadIdx.x;
    for (int i = t; i < NBIN; i += 256)
        lcur[i] = bbbase[i * SCAT_BLOCKS + blockIdx.x];
    __syncthreads();
    int s = blockIdx.x * EPB, e = s + EPB;
    for (int i = s + t; i < e; i += 256) {
        int r   = arow[i];
        int bin = r >> BIN_SHIFT;
        int off = atomicAdd(&lcur[bin], 1);          // LDS atomic
        int drow = r & (BIN_SIZE - 1);
        tmp[off] = make_int2((drow << 17) | acol[i], __float_as_int(aval[i]));
    }
}

__global__ void __launch_bounds__(256) k_binfinal(
        const int* __restrict__ bbbase, const int2* __restrict__ tmp,
        int* __restrict__ row_ptr, int2* __restrict__ edge_s) {
    __shared__ int hist[BIN_SIZE];                   // then reused as cursors
    __shared__ int wsum[4];
    int t = threadIdx.x;
    int bin = blockIdx.x;
    int rbase = bin << BIN_SHIFT;
    int binstart = bbbase[bin * SCAT_BLOCKS];
    int binend   = (bin + 1 < NBIN) ? bbbase[(bin + 1) * SCAT_BLOCKS] : E_EDGES;

    for (int i = t; i < BIN_SIZE; i += 256) hist[i] = 0;
    __syncthreads();
    for (int i = binstart + t; i < binend; i += 256)
        atomicAdd(&hist[((unsigned)tmp[i].x) >> 17], 1);   // LDS atomic
    __syncthreads();

    // 256-thread exclusive scan of hist[1024]: each thread owns 4 elements.
    int lane = t & 63, wid = t >> 6;
    int b4 = t * 4;
    int h0 = hist[b4], h1 = hist[b4 + 1], h2 = hist[b4 + 2], h3 = hist[b4 + 3];
    int tsum = h0 + h1 + h2 + h3;
    int x = tsum;
    #pragma unroll
    for (int off = 1; off < 64; off <<= 1) {
        int y = __shfl_up(x, off);
        if (lane >= off) x += y;
    }
    if (lane == 63) wsum[wid] = x;
    __syncthreads();
    int woff = 0;
    #pragma unroll
    for (int i = 0; i < 4; ++i) if (i < wid) woff += wsum[i];
    int excl = woff + x - tsum;

    int c0 = binstart + excl;
    int c1 = c0 + h0;
    int c2 = c1 + h1;
    int c3 = c2 + h2;
    __syncthreads();
    hist[b4] = c0; hist[b4 + 1] = c1; hist[b4 + 2] = c2; hist[b4 + 3] = c3;
    if (rbase + b4 + 3 < NTOT) {
        row_ptr[rbase + b4]     = c0;
        row_ptr[rbase + b4 + 1] = c1;
        row_ptr[rbase + b4 + 2] = c2;
        row_ptr[rbase + b4 + 3] = c3;
    } else {
        if (rbase + b4     < NTOT) row_ptr[rbase + b4]     = c0;
        if (rbase + b4 + 1 < NTOT) row_ptr[rbase + b4 + 1] = c1;
        if (rbase + b4 + 2 < NTOT) row_ptr[rbase + b4 + 2] = c2;
        if (rbase + b4 + 3 < NTOT) row_ptr[rbase + b4 + 3] = c3;
    }
    if (bin == NBIN - 1 && t == 0) row_ptr[NTOT] = E_EDGES;
    __syncthreads();

    for (int i = binstart + t; i < binend; i += 256) {
        int2 rec = tmp[i];
        int drow = ((unsigned)rec.x) >> 17;
        int pos  = atomicAdd(&hist[drow], 1);        // LDS atomic
        edge_s[pos] = make_int2(rec.x & 0x1FFFF, rec.y);
    }
}

// ---------------------------------------------------------------------------
// SpMM (both hops): dst[row] = bf16( sum val * src[col] ), src/dst bf16.
// Wave = 1 row, split into 4 groups of 16 lanes; each group processes one
// edge, each lane loads uint2 (4 bf16 elems). 2 edge-quads in flight per
// iteration (8 edges). Clamped-index mask handles the tail in-loop.
// Per 8 edges: 4 gather loads + 2 edge loads (vs 16 vmem in the G=64 form).
// ---------------------------------------------------------------------------
__global__ void __launch_bounds__(256) spmm_g4(
        const int* __restrict__ row_ptr, const int2* __restrict__ edge_s,
        const unsigned short* __restrict__ src, unsigned short* __restrict__ dst) {
    int gtid = blockIdx.x * blockDim.x + threadIdx.x;
    int row  = gtid >> 6;
    int lane = gtid & 63;
    if (row >= NTOT) return;
    int g   = lane >> 4;          // edge slot within quad (0..3)
    int sub = lane & 15;          // covers dims 4*sub .. 4*sub+3
    int s = row_ptr[row];
    int e = row_ptr[row + 1];
    float a0 = 0.0f, a1 = 0.0f, a2 = 0.0f, a3 = 0.0f;
    for (int base = s; base < e; base += 8) {
        int i0 = base + g;
        int i1 = base + 4 + g;
        int j0 = (i0 < e) ? i0 : s;          // clamp to a valid record
        int j1 = (i1 < e) ? i1 : s;
        int2 ed0 = edge_s[j0];
        int2 ed1 = edge_s[j1];
        float v0 = (i0 < e) ? __int_as_float(ed0.y) : 0.0f;
        float v1 = (i1 < e) ? __int_as_float(ed1.y) : 0.0f;
        uint2 d0 = *reinterpret_cast<const uint2*>(src + (size_t)ed0.x * DIM + sub * 4);
        uint2 d1 = *reinterpret_cast<const uint2*>(src + (size_t)ed1.x * DIM + sub * 4);
        a0 = fmaf(v0, bflo(d0.x), a0);
        a1 = fmaf(v0, bfhi(d0.x), a1);
        a2 = fmaf(v0, bflo(d0.y), a2);
        a3 = fmaf(v0, bfhi(d0.y), a3);
        a0 = fmaf(v1, bflo(d1.x), a0);
        a1 = fmaf(v1, bfhi(d1.x), a1);
        a2 = fmaf(v1, bflo(d1.y), a2);
        a3 = fmaf(v1, bfhi(d1.y), a3);
    }
    // cross-group reduction: sum the 4 edge-groups' partials
    a0 += __shfl_xor(a0, 16); a0 += __shfl_xor(a0, 32);
    a1 += __shfl_xor(a1, 16); a1 += __shfl_xor(a1, 32);
    a2 += __shfl_xor(a2, 16); a2 += __shfl_xor(a2, 32);
    a3 += __shfl_xor(a3, 16); a3 += __shfl_xor(a3, 32);
    if (g == 0) {
        ushort4 o = make_ushort4(f2bf(a0), f2bf(a1), f2bf(a2), f2bf(a3));
        *reinterpret_cast<ushort4*>(dst + (size_t)row * DIM + (size_t)sub * 4) = o;
    }
}

// ---------------------------------------------------------------------------
// Hop-3 pull for one row over bf16 src (lane = elem layout): sum val*src[col]
// ---------------------------------------------------------------------------
__device__ __forceinline__ float pull_row_h(const int* __restrict__ row_ptr,
                                            const int2* __restrict__ edge_s,
                                            const unsigned short* __restrict__ src,
                                            int row, int lane) {
    int s = row_ptr[row];
    int e = row_ptr[row + 1];
    float acc0 = 0.0f, acc1 = 0.0f;
    for (; s + 8 <= e; s += 8) {
        int2 ed[8];
        #pragma unroll
        for (int i = 0; i < 8; ++i) ed[i] = edge_s[s + i];
        float a[8];
        #pragma unroll
        for (int i = 0; i < 8; ++i) a[i] = bf2f(src[(size_t)ed[i].x * DIM + lane]);
        #pragma unroll
        for (int i = 0; i < 8; i += 2) {
            acc0 = fmaf(__int_as_float(ed[i].y),     a[i],     acc0);
            acc1 = fmaf(__int_as_float(ed[i + 1].y), a[i + 1], acc1);
        }
    }
    if (s < e) {
        int2 ed[8];
        #pragma unroll
        for (int i = 0; i < 8; ++i)
            ed[i] = (s + i < e) ? edge_s[s + i] : make_int2(0, 0);
        float a[8];
        #pragma unroll
        for (int i = 0; i < 8; ++i) a[i] = bf2f(src[(size_t)ed[i].x * DIM + lane]);
        #pragma unroll
        for (int i = 0; i < 8; i += 2) {
            acc0 = fmaf(__int_as_float(ed[i].y),     a[i],     acc0);
            acc1 = fmaf(__int_as_float(ed[i + 1].y), a[i + 1], acc1);
        }
    }
    return acc0 + acc1;
}

// ---------------------------------------------------------------------------
// mean_rows: one wave per (batch, row-type). NO contended atomics.
// ---------------------------------------------------------------------------
__global__ void mean_rows(const unsigned short* __restrict__ side1h,
                          const unsigned short* __restrict__ side2h,
                          const int* __restrict__ row_ptr, const int2* __restrict__ edge_s,
                          const float* __restrict__ ge, const float* __restrict__ de,
                          const float* __restrict__ gt, const float* __restrict__ dt,
                          const int* __restrict__ user, const int* __restrict__ pos,
                          const int* __restrict__ neg, float* __restrict__ mrows,
                          float* __restrict__ regbuf) {
    int gtid = blockIdx.x * blockDim.x + threadIdx.x;
    int wave = gtid >> 6;                  // 0 .. 3*B-1
    int lane = gtid & 63;
    if (wave >= 3 * B_BATCH) return;
    int b = wave / 3;
    int j = wave - 3 * b;                  // 0=user, 1=pos, 2=neg

    int   row;
    float t, e0;
    if (j == 0) {
        int u = user[b];
        row = u;  t = gt[u];  e0 = ge[(size_t)u * DIM + lane];
    } else {
        int d = (j == 1) ? pos[b] : neg[b * K_NEG];
        row = N_G + d;  t = dt[d];  e0 = de[(size_t)d * DIM + lane];
    }
    float w0 = expf(-t);
    float w1 = w0 * t;
    float w2 = w1 * t * 0.5f;
    float w3 = w1 * t * t * (1.0f / 6.0f);

    float s1 = bf2f(side1h[(size_t)row * DIM + lane]);
    float s2 = bf2f(side2h[(size_t)row * DIM + lane]);
    float s3 = pull_row_h(row_ptr, edge_s, side2h, row, lane);
    float m  = 0.25f * (w0 * e0 + w1 * s1 + w2 * s2 + w3 * s3);
    mrows[(size_t)wave * DIM + lane] = m;

    float r0 = w0 * e0;
    float reg = r0 * r0;
    #pragma unroll
    for (int off = 32; off > 0; off >>= 1) reg += __shfl_down(reg, off);
    if (lane == 0) regbuf[wave] = reg;
}

// ---------------------------------------------------------------------------
// loss_dot: one wave per batch element; plain store of per-batch mf term.
// ---------------------------------------------------------------------------
__global__ void loss_dot(const float* __restrict__ mrows, float* __restrict__ mfbuf) {
    int gtid = blockIdx.x * blockDim.x + threadIdx.x;
    int b    = gtid >> 6;
    int lane = gtid & 63;
    if (b >= B_BATCH) return;
    float gm = mrows[(size_t)(3 * b + 0) * DIM + lane];
    float pm = mrows[(size_t)(3 * b + 1) * DIM + lane];
    float nm = mrows[(size_t)(3 * b + 2) * DIM + lane];
    float dotp = gm * pm;
    float dotn = gm * nm;
    #pragma unroll
    for (int off = 32; off > 0; off >>= 1) {
        dotp += __shfl_down(dotp, off);
        dotn += __shfl_down(dotn, off);
    }
    if (lane == 0) {
        float x = dotn - dotp;
        mfbuf[b] = fmaxf(x, 0.0f) + log1pf(expf(-fabsf(x)));   // log1p(exp(x))
    }
}

// ---------------------------------------------------------------------------
// final_reduce: single block sums regbuf (3B) + mfbuf (B), emits 3 outputs.
// ---------------------------------------------------------------------------
__global__ void final_reduce(const float* __restrict__ regbuf,
                             const float* __restrict__ mfbuf,
                             float* __restrict__ out) {
    int t    = threadIdx.x;                // 1024 threads = 16 waves
    int lane = t & 63;
    int wid  = t >> 6;
    float mf = 0.0f, rg = 0.0f;
    for (int i = t; i < B_BATCH; i += 1024)     mf += mfbuf[i];
    for (int i = t; i < 3 * B_BATCH; i += 1024) rg += regbuf[i];
    #pragma unroll
    for (int off = 32; off > 0; off >>= 1) {
        mf += __shfl_down(mf, off);
        rg += __shfl_down(rg, off);
    }
    __shared__ float smf[16], srg[16];
    if (lane == 0) { smf[wid] = mf; srg[wid] = rg; }
    __syncthreads();
    if (t == 0) {
        float M = 0.0f, R = 0.0f;
        #pragma unroll
        for (int i = 0; i < 16; ++i) { M += smf[i]; R += srg[i]; }
        float mfm = M / (float)B_BATCH;
        float emb = DECAY_F * (R * 0.5f) / (float)B_BATCH;
        out[0] = mfm + emb;
        out[1] = mfm;
        out[2] = emb;
    }
}

extern "C" void kernel_launch(void* const* d_in, const int* in_sizes, int n_in,
                              void* d_out, int out_size, void* d_ws, size_t ws_size,
                              hipStream_t stream) {
    const float* ge   = (const float*)d_in[0];
    const float* de   = (const float*)d_in[1];
    const float* gt   = (const float*)d_in[2];
    const float* dt   = (const float*)d_in[3];
    const float* aval = (const float*)d_in[4];
    const int*   arow = (const int*)d_in[5];
    const int*   acol = (const int*)d_in[6];
    const int*   user = (const int*)d_in[7];
    const int*   pos  = (const int*)d_in[8];
    const int*   neg  = (const int*)d_in[9];
    float* out = (float*)d_out;

    // Workspace layout (~68 MB)
    char* ws = (char*)d_ws;
    const size_t rowHBytes = (size_t)NTOT * DIM * sizeof(unsigned short);   // 12.8 MB
    unsigned short* rawh   = (unsigned short*)(ws);
    unsigned short* side1h = (unsigned short*)(ws + rowHBytes);
    unsigned short* side2h = (unsigned short*)(ws + 2 * rowHBytes);
    char* p = ws + 3 * rowHBytes;
    int2*  tmp     = (int2*)p;             p += (size_t)E_EDGES * sizeof(int2);
    int2*  edge_s  = (int2*)p;             p += (size_t)E_EDGES * sizeof(int2);
    float* mrows   = (float*)p;            p += (size_t)3 * B_BATCH * DIM * sizeof(float);
    int*   row_ptr = (int*)p;              p += (NTOT + 1) * sizeof(int);
    int*   bbcnt   = (int*)p;              p += (size_t)NBB * sizeof(int);
    int*   bbbase  = (int*)p;              p += (size_t)NBB * sizeof(int);
    int*   blocksum= (int*)p;              p += 64 * sizeof(int);
    int*   blockoff= (int*)p;              p += 64 * sizeof(int);
    float* regbuf  = (float*)p;            p += (size_t)3 * B_BATCH * sizeof(float);
    float* mfbuf   = (float*)p;

    conv_raw<<<(NTOT * (DIM / 4) + 255) / 256, 256, 0, stream>>>(ge, de, (ushort4*)rawh);

    // CSR build — no global atomics anywhere.
    k_hist1     <<<SCAT_BLOCKS, 256, 0, stream>>>(arow, bbcnt);
    k_scan1g    <<<NB2, 1024, 0, stream>>>(bbcnt, bbbase, blocksum);
    k_scan2g    <<<1, 64, 0, stream>>>(blocksum, blockoff);
    k_scan3g    <<<(NBB + 255) / 256, 256, 0, stream>>>(bbbase, blockoff);
    k_binscatter<<<SCAT_BLOCKS, 256, 0, stream>>>(arow, acol, aval, bbbase, tmp);
    k_binfinal  <<<NBIN, 256, 0, stream>>>(bbbase, tmp, row_ptr, edge_s);

    const int spmm_blocks = (NTOT * 64 + 255) / 256;
    spmm_g4<<<spmm_blocks, 256, 0, stream>>>(row_ptr, edge_s, rawh,   side1h);
    spmm_g4<<<spmm_blocks, 256, 0, stream>>>(row_ptr, edge_s, side1h, side2h);

    mean_rows<<<(3 * B_BATCH * 64 + 255) / 256, 256, 0, stream>>>(
        side1h, side2h, row_ptr, edge_s, ge, de, gt, dt, user, pos, neg, mrows, regbuf);
    loss_dot<<<(B_BATCH * 64 + 255) / 256, 256, 0, stream>>>(mrows, mfbuf);
    final_reduce<<<1, 1024, 0, stream>>>(regbuf, mfbuf, out);
}

// Round 10
// 179.070 us; speedup vs baseline: 3.0603x; 1.0266x over previous
//
#include <hip/hip_runtime.h>
#include <math.h>

// Problem constants (from reference)
#define N_G   60000
#define N_D   40000
#define NTOT  100000          // N_G + N_D
#define DIM   64
#define E_EDGES 1600000
#define B_BATCH 4096
#define K_NEG   1
#define DECAY_F 1e-4f

#define BIN_SHIFT 10
#define BIN_SIZE (1 << BIN_SHIFT)
#define NBIN ((NTOT + BIN_SIZE - 1) >> BIN_SHIFT)   // 98 bins of 1024 rows
#define SCAT_BLOCKS 512
#define EPB (E_EDGES / SCAT_BLOCKS)                 // 3125 edges per block
#define NBB (NBIN * SCAT_BLOCKS)                    // 50176 (block,bin) counters
#define NB2 ((NBB + 1023) / 1024)                   // 49 scan blocks

// bf16 helpers (storage-only; all math in fp32)
__device__ __forceinline__ float bf2f(unsigned short u) {
    return __uint_as_float(((unsigned)u) << 16);
}
__device__ __forceinline__ unsigned short f2bf(float f) {
    unsigned b = __float_as_uint(f);
    return (unsigned short)((b + 0x7FFFu + ((b >> 16) & 1u)) >> 16);
}
// packed-pair unpack: dword holds [lo: elem 2k][hi: elem 2k+1]
__device__ __forceinline__ float bflo(unsigned u) { return __uint_as_float(u << 16); }
__device__ __forceinline__ float bfhi(unsigned u) { return __uint_as_float(u & 0xFFFF0000u); }
// 4-byte edge record: (val_bf15 << 17) | col.  val >= 0 so sign bit is implicit 0.
__device__ __forceinline__ float rec_val(unsigned rec) {
    return __uint_as_float((rec >> 17) << 16);
}

// ---------------------------------------------------------------------------
// conv_raw: rawh = bf16(concat(ge, de)). One thread per 4 floats.
// ---------------------------------------------------------------------------
__global__ void conv_raw(const float* __restrict__ ge, const float* __restrict__ de,
                         ushort4* __restrict__ rawh) {
    int idx = blockIdx.x * blockDim.x + threadIdx.x;   // float4 index
    if (idx >= NTOT * (DIM / 4)) return;
    float4 v = (idx < N_G * (DIM / 4)) ? ((const float4*)ge)[idx]
                                       : ((const float4*)de)[idx - N_G * (DIM / 4)];
    rawh[idx] = make_ushort4(f2bf(v.x), f2bf(v.y), f2bf(v.z), f2bf(v.w));
}

// ---------------------------------------------------------------------------
// CSR build — zero global atomics. hist1 -> scan(bbcnt) -> binscatter -> binfinal
// ---------------------------------------------------------------------------
__global__ void __launch_bounds__(256) k_hist1(const int* __restrict__ arow,
                                               int* __restrict__ bbcnt) {
    __shared__ int cnt[NBIN];
    int t = threadIdx.x;
    for (int i = t; i < NBIN; i += 256) cnt[i] = 0;
    __syncthreads();
    int s = blockIdx.x * EPB, e = s + EPB;
    for (int i = s + t; i < e; i += 256)
        atomicAdd(&cnt[arow[i] >> BIN_SHIFT], 1);    // LDS atomic
    __syncthreads();
    for (int i = t; i < NBIN; i += 256)
        bbcnt[i * SCAT_BLOCKS + blockIdx.x] = cnt[i];
}

__global__ void k_scan1g(const int* __restrict__ in, int* __restrict__ excl,
                         int* __restrict__ blocksum) {
    int gid  = blockIdx.x * 1024 + threadIdx.x;
    int lane = threadIdx.x & 63;
    int wid  = threadIdx.x >> 6;           // 16 waves
    int v = (gid < NBB) ? in[gid] : 0;
    int x = v;
    #pragma unroll
    for (int off = 1; off < 64; off <<= 1) {
        int y = __shfl_up(x, off);
        if (lane >= off) x += y;
    }
    __shared__ int wsum[16];
    if (lane == 63) wsum[wid] = x;
    __syncthreads();
    if (wid == 0) {
        int w = (lane < 16) ? wsum[lane] : 0;
        #pragma unroll
        for (int off = 1; off < 16; off <<= 1) {
            int y = __shfl_up(w, off);
            if (lane >= off) w += y;
        }
        if (lane < 16) wsum[lane] = w;
    }
    __syncthreads();
    int woff = (wid == 0) ? 0 : wsum[wid - 1];
    int incl = x + woff;
    if (gid < NBB) excl[gid] = incl - v;
    if (threadIdx.x == 1023) blocksum[blockIdx.x] = incl;
}

__global__ void k_scan2g(const int* __restrict__ blocksum, int* __restrict__ blockoff) {
    int t = threadIdx.x;                   // 0..63 (NB2=49 fits one wave)
    int v = (t < NB2) ? blocksum[t] : 0;
    int x = v;
    #pragma unroll
    for (int off = 1; off < 64; off <<= 1) {
        int y = __shfl_up(x, off);
        if (t >= off) x += y;
    }
    if (t < NB2) blockoff[t] = x - v;
}

__global__ void k_scan3g(int* __restrict__ excl, const int* __restrict__ blockoff) {
    int gid = blockIdx.x * blockDim.x + threadIdx.x;
    if (gid < NBB) excl[gid] += blockoff[gid >> 10];
}

__global__ void __launch_bounds__(256) k_binscatter(
        const int* __restrict__ arow, const int* __restrict__ acol,
        const float* __restrict__ aval, const int* __restrict__ bbbase,
        int2* __restrict__ tmp) {
    __shared__ int lcur[NBIN];
    int t = threadIdx.x;
    for (int i = t; i < NBIN; i += 256)
        lcur[i] = bbbase[i * SCAT_BLOCKS + blockIdx.x];
    __syncthreads();
    int s = blockIdx.x * EPB, e = s + EPB;
    for (int i = s + t; i < e; i += 256) {
        int r   = arow[i];
        int bin = r >> BIN_SHIFT;
        int off = atomicAdd(&lcur[bin], 1);          // LDS atomic
        int drow = r & (BIN_SIZE - 1);
        tmp[off] = make_int2((drow << 17) | acol[i], __float_as_int(aval[i]));
    }
}

// Per bin: LDS row-histogram + local scan -> row_ptr (coalesced) + final scatter
// into 4-byte compressed edge records.
__global__ void __launch_bounds__(256) k_binfinal(
        const int* __restrict__ bbbase, const int2* __restrict__ tmp,
        int* __restrict__ row_ptr, unsigned* __restrict__ edge_c) {
    __shared__ int hist[BIN_SIZE];                   // then reused as cursors
    __shared__ int wsum[4];
    int t = threadIdx.x;
    int bin = blockIdx.x;
    int rbase = bin << BIN_SHIFT;
    int binstart = bbbase[bin * SCAT_BLOCKS];
    int binend   = (bin + 1 < NBIN) ? bbbase[(bin + 1) * SCAT_BLOCKS] : E_EDGES;

    for (int i = t; i < BIN_SIZE; i += 256) hist[i] = 0;
    __syncthreads();
    for (int i = binstart + t; i < binend; i += 256)
        atomicAdd(&hist[((unsigned)tmp[i].x) >> 17], 1);   // LDS atomic
    __syncthreads();

    // 256-thread exclusive scan of hist[1024]: each thread owns 4 elements.
    int lane = t & 63, wid = t >> 6;
    int b4 = t * 4;
    int h0 = hist[b4], h1 = hist[b4 + 1], h2 = hist[b4 + 2], h3 = hist[b4 + 3];
    int tsum = h0 + h1 + h2 + h3;
    int x = tsum;
    #pragma unroll
    for (int off = 1; off < 64; off <<= 1) {
        int y = __shfl_up(x, off);
        if (lane >= off) x += y;
    }
    if (lane == 63) wsum[wid] = x;
    __syncthreads();
    int woff = 0;
    #pragma unroll
    for (int i = 0; i < 4; ++i) if (i < wid) woff += wsum[i];
    int excl = woff + x - tsum;

    int c0 = binstart + excl;
    int c1 = c0 + h0;
    int c2 = c1 + h1;
    int c3 = c2 + h2;
    __syncthreads();
    hist[b4] = c0; hist[b4 + 1] = c1; hist[b4 + 2] = c2; hist[b4 + 3] = c3;
    if (rbase + b4 + 3 < NTOT) {
        row_ptr[rbase + b4]     = c0;
        row_ptr[rbase + b4 + 1] = c1;
        row_ptr[rbase + b4 + 2] = c2;
        row_ptr[rbase + b4 + 3] = c3;
    } else {
        if (rbase + b4     < NTOT) row_ptr[rbase + b4]     = c0;
        if (rbase + b4 + 1 < NTOT) row_ptr[rbase + b4 + 1] = c1;
        if (rbase + b4 + 2 < NTOT) row_ptr[rbase + b4 + 2] = c2;
        if (rbase + b4 + 3 < NTOT) row_ptr[rbase + b4 + 3] = c3;
    }
    if (bin == NBIN - 1 && t == 0) row_ptr[NTOT] = E_EDGES;
    __syncthreads();

    for (int i = binstart + t; i < binend; i += 256) {
        int2 rec = tmp[i];
        int drow = ((unsigned)rec.x) >> 17;
        int pos  = atomicAdd(&hist[drow], 1);        // LDS atomic
        unsigned vb = (unsigned)rec.y;
        unsigned b  = (vb + 0x7FFFu + ((vb >> 16) & 1u)) >> 16;   // bf16 round
        edge_c[pos] = ((b & 0x7FFFu) << 17) | ((unsigned)rec.x & 0x1FFFFu);
    }
}

// ---------------------------------------------------------------------------
// SpMM (both hops): dst[row] = bf16( sum val * src[col] ), src/dst bf16.
// Wave = 1 row, 8 groups of 8 lanes; each group = one edge, each lane loads
// uint4 (16 B = 8 bf16). ONE gather instr + ONE edge-load instr per 8 edges.
// Clamped-index mask handles the tail in-loop. 32-bit premultiplied offsets.
// ---------------------------------------------------------------------------
__global__ void __launch_bounds__(256) spmm_g8(
        const int* __restrict__ row_ptr, const unsigned* __restrict__ edge_c,
        const unsigned short* __restrict__ src, unsigned short* __restrict__ dst) {
    int gtid = blockIdx.x * blockDim.x + threadIdx.x;
    int row  = gtid >> 6;
    int lane = gtid & 63;
    if (row >= NTOT) return;
    int g    = lane >> 3;         // edge slot (0..7)
    int sub  = lane & 7;          // 16B chunk of the gathered row
    int s = row_ptr[row];
    int e = row_ptr[row + 1];
    const char* srcb = (const char*)src;
    float a0 = 0.f, a1 = 0.f, a2 = 0.f, a3 = 0.f;
    float a4 = 0.f, a5 = 0.f, a6 = 0.f, a7 = 0.f;
    for (int base = s; base < e; base += 8) {
        int i = base + g;
        int j = (i < e) ? i : s;                     // clamp to a valid record
        unsigned rec = edge_c[j];
        float v = (i < e) ? rec_val(rec) : 0.0f;
        unsigned coff = (rec & 0x1FFFFu) << 7;       // byte offset of row (128B)
        uint4 d = *reinterpret_cast<const uint4*>(srcb + coff + sub * 16);
        a0 = fmaf(v, bflo(d.x), a0);
        a1 = fmaf(v, bfhi(d.x), a1);
        a2 = fmaf(v, bflo(d.y), a2);
        a3 = fmaf(v, bfhi(d.y), a3);
        a4 = fmaf(v, bflo(d.z), a4);
        a5 = fmaf(v, bfhi(d.z), a5);
        a6 = fmaf(v, bflo(d.w), a6);
        a7 = fmaf(v, bfhi(d.w), a7);
    }
    // butterfly across the 8 edge-groups (same sub exchanges)
    #pragma unroll
    for (int off = 8; off < 64; off <<= 1) {
        a0 += __shfl_xor(a0, off);
        a1 += __shfl_xor(a1, off);
        a2 += __shfl_xor(a2, off);
        a3 += __shfl_xor(a3, off);
        a4 += __shfl_xor(a4, off);
        a5 += __shfl_xor(a5, off);
        a6 += __shfl_xor(a6, off);
        a7 += __shfl_xor(a7, off);
    }
    if (g == 0) {
        uint4 o;
        o.x = (unsigned)f2bf(a0) | ((unsigned)f2bf(a1) << 16);
        o.y = (unsigned)f2bf(a2) | ((unsigned)f2bf(a3) << 16);
        o.z = (unsigned)f2bf(a4) | ((unsigned)f2bf(a5) << 16);
        o.w = (unsigned)f2bf(a6) | ((unsigned)f2bf(a7) << 16);
        *reinterpret_cast<uint4*>(dst + (size_t)row * DIM + (size_t)sub * 8) = o;
    }
}

// ---------------------------------------------------------------------------
// Hop-3 pull for one row over bf16 src (lane = elem layout), 4B edge records.
// ---------------------------------------------------------------------------
__device__ __forceinline__ float pull_row_h(const int* __restrict__ row_ptr,
                                            const unsigned* __restrict__ edge_c,
                                            const unsigned short* __restrict__ src,
                                            int row, int lane) {
    int s = row_ptr[row];
    int e = row_ptr[row + 1];
    float acc0 = 0.0f, acc1 = 0.0f;
    for (; s + 8 <= e; s += 8) {
        unsigned ed[8];
        #pragma unroll
        for (int i = 0; i < 8; ++i) ed[i] = edge_c[s + i];
        float a[8];
        #pragma unroll
        for (int i = 0; i < 8; ++i)
            a[i] = bf2f(src[(size_t)(ed[i] & 0x1FFFFu) * DIM + lane]);
        #pragma unroll
        for (int i = 0; i < 8; i += 2) {
            acc0 = fmaf(rec_val(ed[i]),     a[i],     acc0);
            acc1 = fmaf(rec_val(ed[i + 1]), a[i + 1], acc1);
        }
    }
    if (s < e) {
        unsigned ed[8];
        #pragma unroll
        for (int i = 0; i < 8; ++i)
            ed[i] = (s + i < e) ? edge_c[s + i] : 0u;
        float a[8];
        #pragma unroll
        for (int i = 0; i < 8; ++i)
            a[i] = bf2f(src[(size_t)(ed[i] & 0x1FFFFu) * DIM + lane]);
        #pragma unroll
        for (int i = 0; i < 8; i += 2) {
            acc0 = fmaf(rec_val(ed[i]),     a[i],     acc0);
            acc1 = fmaf(rec_val(ed[i + 1]), a[i + 1], acc1);
        }
    }
    return acc0 + acc1;
}

// ---------------------------------------------------------------------------
// mean_rows: one wave per (batch, row-type). NO contended atomics.
// ---------------------------------------------------------------------------
__global__ void mean_rows(const unsigned short* __restrict__ side1h,
                          const unsigned short* __restrict__ side2h,
                          const int* __restrict__ row_ptr, const unsigned* __restrict__ edge_c,
                          const float* __restrict__ ge, const float* __restrict__ de,
                          const float* __restrict__ gt, const float* __restrict__ dt,
                          const int* __restrict__ user, const int* __restrict__ pos,
                          const int* __restrict__ neg, float* __restrict__ mrows,
                          float* __restrict__ regbuf) {
    int gtid = blockIdx.x * blockDim.x + threadIdx.x;
    int wave = gtid >> 6;                  // 0 .. 3*B-1
    int lane = gtid & 63;
    if (wave >= 3 * B_BATCH) return;
    int b = wave / 3;
    int j = wave - 3 * b;                  // 0=user, 1=pos, 2=neg

    int   row;
    float t, e0;
    if (j == 0) {
        int u = user[b];
        row = u;  t = gt[u];  e0 = ge[(size_t)u * DIM + lane];
    } else {
        int d = (j == 1) ? pos[b] : neg[b * K_NEG];
        row = N_G + d;  t = dt[d];  e0 = de[(size_t)d * DIM + lane];
    }
    float w0 = expf(-t);
    float w1 = w0 * t;
    float w2 = w1 * t * 0.5f;
    float w3 = w1 * t * t * (1.0f / 6.0f);

    float s1 = bf2f(side1h[(size_t)row * DIM + lane]);
    float s2 = bf2f(side2h[(size_t)row * DIM + lane]);
    float s3 = pull_row_h(row_ptr, edge_c, side2h, row, lane);
    float m  = 0.25f * (w0 * e0 + w1 * s1 + w2 * s2 + w3 * s3);
    mrows[(size_t)wave * DIM + lane] = m;

    float r0 = w0 * e0;
    float reg = r0 * r0;
    #pragma unroll
    for (int off = 32; off > 0; off >>= 1) reg += __shfl_down(reg, off);
    if (lane == 0) regbuf[wave] = reg;
}

// ---------------------------------------------------------------------------
// loss_dot: one wave per batch element; plain store of per-batch mf term.
// ---------------------------------------------------------------------------
__global__ void loss_dot(const float* __restrict__ mrows, float* __restrict__ mfbuf) {
    int gtid = blockIdx.x * blockDim.x + threadIdx.x;
    int b    = gtid >> 6;
    int lane = gtid & 63;
    if (b >= B_BATCH) return;
    float gm = mrows[(size_t)(3 * b + 0) * DIM + lane];
    float pm = mrows[(size_t)(3 * b + 1) * DIM + lane];
    float nm = mrows[(size_t)(3 * b + 2) * DIM + lane];
    float dotp = gm * pm;
    float dotn = gm * nm;
    #pragma unroll
    for (int off = 32; off > 0; off >>= 1) {
        dotp += __shfl_down(dotp, off);
        dotn += __shfl_down(dotn, off);
    }
    if (lane == 0) {
        float x = dotn - dotp;
        mfbuf[b] = fmaxf(x, 0.0f) + log1pf(expf(-fabsf(x)));   // log1p(exp(x))
    }
}

// ---------------------------------------------------------------------------
// final_reduce: single block sums regbuf (3B) + mfbuf (B), emits 3 outputs.
// ---------------------------------------------------------------------------
__global__ void final_reduce(const float* __restrict__ regbuf,
                             const float* __restrict__ mfbuf,
                             float* __restrict__ out) {
    int t    = threadIdx.x;                // 1024 threads = 16 waves
    int lane = t & 63;
    int wid  = t >> 6;
    float mf = 0.0f, rg = 0.0f;
    for (int i = t; i < B_BATCH; i += 1024)     mf += mfbuf[i];
    for (int i = t; i < 3 * B_BATCH; i += 1024) rg += regbuf[i];
    #pragma unroll
    for (int off = 32; off > 0; off >>= 1) {
        mf += __shfl_down(mf, off);
        rg += __shfl_down(rg, off);
    }
    __shared__ float smf[16], srg[16];
    if (lane == 0) { smf[wid] = mf; srg[wid] = rg; }
    __syncthreads();
    if (t == 0) {
        float M = 0.0f, R = 0.0f;
        #pragma unroll
        for (int i = 0; i < 16; ++i) { M += smf[i]; R += srg[i]; }
        float mfm = M / (float)B_BATCH;
        float emb = DECAY_F * (R * 0.5f) / (float)B_BATCH;
        out[0] = mfm + emb;
        out[1] = mfm;
        out[2] = emb;
    }
}

extern "C" void kernel_launch(void* const* d_in, const int* in_sizes, int n_in,
                              void* d_out, int out_size, void* d_ws, size_t ws_size,
                              hipStream_t stream) {
    const float* ge   = (const float*)d_in[0];
    const float* de   = (const float*)d_in[1];
    const float* gt   = (const float*)d_in[2];
    const float* dt   = (const float*)d_in[3];
    const float* aval = (const float*)d_in[4];
    const int*   arow = (const int*)d_in[5];
    const int*   acol = (const int*)d_in[6];
    const int*   user = (const int*)d_in[7];
    const int*   pos  = (const int*)d_in[8];
    const int*   neg  = (const int*)d_in[9];
    float* out = (float*)d_out;

    // Workspace layout (~62 MB)
    char* ws = (char*)d_ws;
    const size_t rowHBytes = (size_t)NTOT * DIM * sizeof(unsigned short);   // 12.8 MB
    unsigned short* rawh   = (unsigned short*)(ws);
    unsigned short* side1h = (unsigned short*)(ws + rowHBytes);
    unsigned short* side2h = (unsigned short*)(ws + 2 * rowHBytes);
    char* p = ws + 3 * rowHBytes;
    int2*     tmp     = (int2*)p;          p += (size_t)E_EDGES * sizeof(int2);
    unsigned* edge_c  = (unsigned*)p;      p += (size_t)E_EDGES * sizeof(unsigned);
    float*    mrows   = (float*)p;         p += (size_t)3 * B_BATCH * DIM * sizeof(float);
    int*      row_ptr = (int*)p;           p += (NTOT + 1) * sizeof(int);
    int*      bbcnt   = (int*)p;           p += (size_t)NBB * sizeof(int);
    int*      bbbase  = (int*)p;           p += (size_t)NBB * sizeof(int);
    int*      blocksum= (int*)p;           p += 64 * sizeof(int);
    int*      blockoff= (int*)p;           p += 64 * sizeof(int);
    float*    regbuf  = (float*)p;         p += (size_t)3 * B_BATCH * sizeof(float);
    float*    mfbuf   = (float*)p;

    conv_raw<<<(NTOT * (DIM / 4) + 255) / 256, 256, 0, stream>>>(ge, de, (ushort4*)rawh);

    // CSR build — no global atomics anywhere.
    k_hist1     <<<SCAT_BLOCKS, 256, 0, stream>>>(arow, bbcnt);
    k_scan1g    <<<NB2, 1024, 0, stream>>>(bbcnt, bbbase, blocksum);
    k_scan2g    <<<1, 64, 0, stream>>>(blocksum, blockoff);
    k_scan3g    <<<(NBB + 255) / 256, 256, 0, stream>>>(bbbase, blockoff);
    k_binscatter<<<SCAT_BLOCKS, 256, 0, stream>>>(arow, acol, aval, bbbase, tmp);
    k_binfinal  <<<NBIN, 256, 0, stream>>>(bbbase, tmp, row_ptr, edge_c);

    const int spmm_blocks = (NTOT * 64 + 255) / 256;
    spmm_g8<<<spmm_blocks, 256, 0, stream>>>(row_ptr, edge_c, rawh,   side1h);
    spmm_g8<<<spmm_blocks, 256, 0, stream>>>(row_ptr, edge_c, side1h, side2h);

    mean_rows<<<(3 * B_BATCH * 64 + 255) / 256, 256, 0, stream>>>(
        side1h, side2h, row_ptr, edge_c, ge, de, gt, dt, user, pos, neg, mrows, regbuf);
    loss_dot<<<(B_BATCH * 64 + 255) / 256, 256, 0, stream>>>(mrows, mfbuf);
    final_reduce<<<1, 1024, 0, stream>>>(regbuf, mfbuf, out);
}